// Round 14
// baseline (975.710 us; speedup 1.0000x reference)
//
#include <hip/hip_runtime.h>
#include <math.h>

#define NAg 8000
#define NTr 30000
#define NE  150000

// ---- workspace layout (float offsets) ----
#define XA_OFF 0          // 8000*64
#define XT_OFF 512000     // 30000*64
#define H0_OFF 2432000    // bf16 interleaved [node][c*4+h], 256 ushorts/node
#define H1_OFF 4480000
#define H2_OFF 12160000
#define H3_OFF 14208000   // bf16 ends at float 18048000
#define BNSTB 8320000     // 64 buckets x [2][128] = 16384 floats
#define WVB   8336384     // [layer][side*4+r][256] = 6144 floats
#define W2B   8342528     // [layer][r][64][256] fp32 interleaved = 196608 floats
#define CSTB  18100000    // 64 buckets x [type][192] = 24576 floats
#define ALS0 21888000
#define ALS1 21920000
#define ALS2 22040000
#define ALS3 22072000
#define ALD0 22192000
#define ALD1 22312000
#define ALD2 22344000
#define ALD3 22464000
#define ESRC_I 22496000   // int offsets into (int*)ws; 4 x 150000
#define OAACC 23104000    // 8000*64
#define OTACC 23616000    // 30000*64
#define BNST 25536000     // [type: 0 agent,1 track][2][64]
#define ROWP_I 25536640   // 4 x 30016 ints
#define CURS_I 25656704   // 4 x 30016 ints
#define RELSTRIDE 30016

typedef unsigned short ushortT;

__device__ __forceinline__ float lrelu(float x){ return x >= 0.f ? x : 0.2f*x; }
__device__ __forceinline__ unsigned fmap(float f){ unsigned u=__float_as_uint(f); return (u&0x80000000u)? ~u : (u|0x80000000u); }
__device__ __forceinline__ float funmap(unsigned u){ return (u&0x80000000u)? __uint_as_float(u&0x7FFFFFFFu) : __uint_as_float(~u); }
__device__ __forceinline__ float softplusf(float x){ return fmaxf(x,0.f) + log1pf(expf(-fabsf(x))); }
__device__ __forceinline__ ushortT f2bf(float f){
  unsigned u = __float_as_uint(f);
  unsigned r = u + 0x7FFFu + ((u>>16)&1u);   // RNE
  return (ushortT)(r>>16);
}
__device__ __forceinline__ float bf2f(ushortT s){ return __uint_as_float(((unsigned)s)<<16); }
__device__ __forceinline__ float wred32(float v){
  #pragma unroll
  for (int o=16;o;o>>=1) v += __shfl_xor(v,o,32);
  return v;
}
__device__ __forceinline__ int selH(int r){ return r==0?H0_OFF: r==1?H1_OFF: r==2?H2_OFF:H3_OFF; }
__device__ __forceinline__ int selALS(int r){ return r==0?ALS0: r==1?ALS1: r==2?ALS2:ALS3; }
__device__ __forceinline__ int selALD(int r){ return r==0?ALD0: r==1?ALD1: r==2?ALD2:ALD3; }

// per-relation softmax-weighted aggregation for one node's edge list (shuffle version)
__device__ __forceinline__ float agg_rel(const int* es, int p, int p1, const float* als,
                                         const ushortT* h16, float ad, int lane, int hh, int base) {
  float num0=0.f, num1=0.f, num2=0.f, num3=0.f, den=0.f;
  for (; p + 4 <= p1; p += 4) {
    int sa = es[p], sb = es[p+1], sc = es[p+2], sd4 = es[p+3];
    ushort4 va = *(const ushort4*)(h16 + (size_t)sa*256 + lane*4);
    ushort4 vb = *(const ushort4*)(h16 + (size_t)sb*256 + lane*4);
    ushort4 vc = *(const ushort4*)(h16 + (size_t)sc*256 + lane*4);
    ushort4 vd = *(const ushort4*)(h16 + (size_t)sd4*256 + lane*4);
    float la = als[sa*4+hh], lb = als[sb*4+hh], lc = als[sc*4+hh], ld = als[sd4*4+hh];
    float ea = __expf(lrelu(la + ad));
    float eb = __expf(lrelu(lb + ad));
    float ec = __expf(lrelu(lc + ad));
    float ed = __expf(lrelu(ld + ad));
    den += (ea+eb)+(ec+ed);
    float qa0=__shfl(ea,base), qa1=__shfl(ea,base+1), qa2=__shfl(ea,base+2), qa3=__shfl(ea,base+3);
    float qb0=__shfl(eb,base), qb1=__shfl(eb,base+1), qb2=__shfl(eb,base+2), qb3=__shfl(eb,base+3);
    float qc0=__shfl(ec,base), qc1=__shfl(ec,base+1), qc2=__shfl(ec,base+2), qc3=__shfl(ec,base+3);
    float qd0=__shfl(ed,base), qd1=__shfl(ed,base+1), qd2=__shfl(ed,base+2), qd3=__shfl(ed,base+3);
    num0 += qa0*bf2f(va.x) + qb0*bf2f(vb.x) + qc0*bf2f(vc.x) + qd0*bf2f(vd.x);
    num1 += qa1*bf2f(va.y) + qb1*bf2f(vb.y) + qc1*bf2f(vc.y) + qd1*bf2f(vd.y);
    num2 += qa2*bf2f(va.z) + qb2*bf2f(vb.z) + qc2*bf2f(vc.z) + qd2*bf2f(vd.z);
    num3 += qa3*bf2f(va.w) + qb3*bf2f(vb.w) + qc3*bf2f(vc.w) + qd3*bf2f(vd.w);
  }
  for (; p < p1; ++p) {
    int s = es[p];
    ushort4 va = *(const ushort4*)(h16 + (size_t)s*256 + lane*4);
    float e = __expf(lrelu(als[s*4 + hh] + ad));
    den += e;
    float q0 = __shfl(e, base), q1 = __shfl(e, base+1), q2 = __shfl(e, base+2), q3 = __shfl(e, base+3);
    num0 += q0*bf2f(va.x); num1 += q1*bf2f(va.y); num2 += q2*bf2f(va.z); num3 += q3*bf2f(va.w);
  }
  float rd = 1.f/(den + 1e-16f);
  float r0 = __shfl(rd, base), r1 = __shfl(rd, base+1), r2 = __shfl(rd, base+2), r3 = __shfl(rd, base+3);
  return num0*r0 + num1*r1 + num2*r2 + num3*r3;
}

// ---------------- pre: encoder + CSR histogram + weight prep, one kernel ----------------
__global__ __launch_bounds__(256) void k_pre(const float* xA, const float* xT,
    const float* aeW, const float* aeB, const float* teW, const float* teB,
    const int* d0_, const int* d1_, const int* d2_, const int* d3_,
    const float* convW, const float* convAsrc, const float* convAdst, float* ws) {
  int bid = blockIdx.x;
  int t = threadIdx.x;
  __shared__ float xs[4][48];
  if (bid < 9500) {
    // encoder
    int wv = t >> 6, lane = t & 63;
    int type, nb;
    if (bid < 2000) { type = 0; nb = bid; } else { type = 1; nb = bid - 2000; }
    int n = nb*4 + wv;
    int F = type ? 48 : 32;
    const float* X = type ? xT : xA;
    const float* W = type ? teW : aeW;
    const float* B = type ? teB : aeB;
    float* out = ws + (type ? XT_OFF : XA_OFF);
    if (lane < F) xs[wv][lane] = X[(size_t)n*F + lane];
    __syncthreads();
    float acc = B[lane];
    for (int k = 0; k < F; ++k) acc += xs[wv][k] * W[k*64 + lane];
    out[(size_t)n*64 + lane] = fmaxf(acc, 0.f);
  } else if (bid < 11844) {
    // CSR histogram
    int idx = bid - 9500;
    int r = idx / 586, eb = idx % 586;
    const int* dp = r==0? d0_ : r==1? d1_ : r==2? d2_ : d3_;
    int e = eb*256 + t;
    if (e < NE) atomicAdd(&((int*)ws)[ROWP_I + r*RELSTRIDE + dp[e]], 1);
  } else {
    // weight prep: W2 relayout + Wv vectors
    int lr = bid - 11844;            // layer*4 + r
    int layer = lr >> 2, r = lr & 3;
    const float* W = convW + (size_t)lr*64*256;
    float* W2 = ws + W2B + (size_t)lr*64*256;
    int c = t >> 2, h = t & 3;
    for (int k = 0; k < 64; ++k) W2[k*256 + t] = W[k*256 + h*64 + c];
    int k = t >> 2;
    const float* ad = convAdst + (size_t)lr*256;
    const float* as = convAsrc + (size_t)lr*256;
    float s0 = 0.f, s1 = 0.f;
    for (int cc = 0; cc < 64; ++cc) {
      float w = W[k*256 + h*64 + cc];
      s0 += w * ad[h*64 + cc];
      s1 += w * as[h*64 + cc];
    }
    ws[WVB + (size_t)(layer*8 + 0*4 + r)*256 + t] = s0;   // side 0: ald
    ws[WVB + (size_t)(layer*8 + 1*4 + r)*256 + t] = s1;   // side 1: als
  }
}

// ---------------- CSR build: exclusive scan per relation ----------------
__global__ __launch_bounds__(256) void k_scan(int* wsi) {
  int r = blockIdx.x;
  int n = ((r & 1) ? NAg : NTr) + 1;
  int* rp = wsi + ROWP_I + r*RELSTRIDE;
  __shared__ int part[256];
  int t = threadIdx.x;
  int chunk = (n + 255) / 256;
  int lo = t*chunk, hi = min(lo + chunk, n);
  int s = 0;
  for (int i = lo; i < hi; ++i) s += rp[i];
  part[t] = s;
  __syncthreads();
  if (t == 0) {
    int run = 0;
    for (int i = 0; i < 256; ++i) { int tm = part[i]; part[i] = run; run += tm; }
  }
  __syncthreads();
  int run = part[t];
  for (int i = lo; i < hi; ++i) { int tm = rp[i]; rp[i] = run; run += tm; }
}

// ---------------- CSR build: fill sorted src lists ----------------
__global__ __launch_bounds__(256) void k_fill(const int* s0,const int* d0_,const int* s1,const int* d1_,
    const int* s2,const int* d2_,const int* s3,const int* d3_, int* wsi) {
  int r = blockIdx.y;
  const int* sp = r==0? s0 : r==1? s1 : r==2? s2 : s3;
  const int* dp = r==0? d0_ : r==1? d1_ : r==2? d2_ : d3_;
  int e = blockIdx.x*256 + threadIdx.x;
  if (e >= NE) return;
  int d = dp[e];
  int pos = wsi[ROWP_I + r*RELSTRIDE + d] + atomicAdd(&wsi[CURS_I + r*RELSTRIDE + d], 1);
  wsi[ESRC_I + r*NE + pos] = sp[e];
}

// ---------------- fused per-layer compute: BN(prev)+residual, GEMMs (both rels), als/ald ----------------
// mode: 0 = no BN (layer 0); 1 = BN(l-1), no residual; 2 = BN(l-1) + residual
__global__ __launch_bounds__(256) void k_fusedA(const float* bnG, const float* bnB, float* ws,
                                                int layer, int mode) {
  int bid = blockIdx.x;
  int t = threadIdx.x;
  if (bid < 64) ws[BNSTB + bid*256 + t] = 0.f;   // zero BN-stat buckets for this layer's agg
  int tau, row0;
  if (bid < 500) { tau = 0; row0 = bid*16; }
  else           { tau = 1; row0 = (bid-500)*16; }
  float* x = ws + (tau ? XT_OFF : XA_OFF);
  const float* acc_t = ws + (tau ? OTACC : OAACC);
  __shared__ float xs[16][64];
  if (mode == 0) {
    #pragma unroll
    for (int i = 0; i < 4; ++i) {
      int lin = i*256 + t; int rw = lin>>6, k = lin&63;
      xs[rw][k] = x[((size_t)row0+rw)*64 + k];
    }
  } else {
    int lm1 = layer - 1;
    float Nf = tau ? 30000.f : 8000.f;
    #pragma unroll
    for (int i = 0; i < 4; ++i) {
      int lin = i*256 + t; int rw = lin>>6, k = lin&63;
      size_t gi = ((size_t)row0+rw)*64 + k;
      float s1 = ws[BNST + tau*128 + k], s2 = ws[BNST + tau*128 + 64 + k];
      float mu = s1/Nf, var = s2/Nf - mu*mu;
      float g = bnG[(lm1*2+tau)*64 + k], b = bnB[(lm1*2+tau)*64 + k];
      float y = g*(acc_t[gi]-mu)*rsqrtf(var+1e-5f) + b;
      if (mode == 2) y += x[gi];
      x[gi] = y;
      xs[rw][k] = y;
    }
  }
  __syncthreads();
  // vec phase: als/ald for these 16 nodes (4 tasks x 4 heads x 16 nodes = 256 threads)
  {
    int node = t >> 4, task = (t >> 2) & 3, h = t & 3;
    int y_, off_;
    if (tau == 0) {
      if (task == 0)      { y_ = 4; off_ = ALS0; }
      else if (task == 1) { y_ = 6; off_ = ALS2; }
      else if (task == 2) { y_ = 1; off_ = ALD1; }
      else                { y_ = 3; off_ = ALD3; }
    } else {
      if (task == 0)      { y_ = 5; off_ = ALS1; }
      else if (task == 1) { y_ = 7; off_ = ALS3; }
      else if (task == 2) { y_ = 0; off_ = ALD0; }
      else                { y_ = 2; off_ = ALD2; }
    }
    const float* Wv = ws + WVB + (size_t)(layer*8 + y_)*256;
    float s = 0.f;
    #pragma unroll
    for (int k = 0; k < 64; ++k) s += xs[node][k] * Wv[k*4 + h];
    ws[off_ + (size_t)(row0 + node)*4 + h] = s;
  }
  // GEMM phase: both relations sharing this src type
  int c0 = t & 63, tr = t >> 6;
  #pragma unroll
  for (int rr_ = 0; rr_ < 2; ++rr_) {
    int r = tau ? (rr_ ? 3 : 1) : (rr_ ? 2 : 0);
    const float* W2 = ws + W2B + (size_t)(layer*4 + r)*64*256;
    ushortT* h16 = (ushortT*)(ws + selH(r));
    float acc[4][4];
    #pragma unroll
    for (int i=0;i<4;i++){ acc[i][0]=0;acc[i][1]=0;acc[i][2]=0;acc[i][3]=0; }
    const float* Wc = W2 + c0*4;
    for (int k4 = 0; k4 < 16; ++k4) {
      float4 xv[4];
      #pragma unroll
      for (int i = 0; i < 4; ++i) xv[i] = *(const float4*)&xs[tr*4+i][k4*4];
      #pragma unroll
      for (int kk = 0; kk < 4; ++kk) {
        int k = k4*4 + kk;
        float4 w4 = *(const float4*)(Wc + k*256);
        #pragma unroll
        for (int i = 0; i < 4; ++i) {
          float xvv = (kk==0)?xv[i].x:(kk==1)?xv[i].y:(kk==2)?xv[i].z:xv[i].w;
          acc[i][0] += xvv*w4.x; acc[i][1] += xvv*w4.y; acc[i][2] += xvv*w4.z; acc[i][3] += xvv*w4.w;
        }
      }
    }
    #pragma unroll
    for (int i = 0; i < 4; ++i) {
      int row = row0 + tr*4 + i;
      ushort4 pk;
      pk.x = f2bf(acc[i][0]); pk.y = f2bf(acc[i][1]);
      pk.z = f2bf(acc[i][2]); pk.w = f2bf(acc[i][3]);
      *(ushort4*)(h16 + (size_t)row*256 + c0*4) = pk;
    }
  }
}

// ---------------- fused CSR aggregation, flattened grid, agents-first ----------------
__global__ __launch_bounds__(256) void k_agg(const float* convBias, float* ws, int layer) {
  int t = threadIdx.x, wv = t >> 6, lane = t & 63, hh = lane & 3, base = lane & ~3;
  const int* wsi = (const int*)ws;
  int bid = blockIdx.x;
  __shared__ float part[4][64];
  __shared__ float sh1[4][64];
  __shared__ float sh2[4][64];
  if (bid < 4000) {
    int node = bid*2 + (wv >> 1);
    int rr = wv & 1;
    int r = rr ? 3 : 1;
    const int* rp = wsi + ROWP_I + r*RELSTRIDE;
    const int* es = wsi + ESRC_I + r*NE;
    const float* als = ws + selALS(r);
    const ushortT* h16 = (const ushortT*)(ws + selH(r));
    float ad = (ws + selALD(r))[node*4 + hh];
    part[wv][lane] = agg_rel(es, rp[node], rp[node+1], als, h16, ad, lane, hh, base);
    __syncthreads();
    if (rr == 0) {
      float o = part[wv][lane] + part[wv+1][lane];
      float bavg = 0.5f*(convBias[(layer*4 + 1)*64 + lane] + convBias[(layer*4 + 3)*64 + lane]);
      float z = fmaxf(o*0.125f + bavg, 0.f);
      ws[OAACC + (size_t)node*64 + lane] = z;
      sh1[wv][lane] = z; sh2[wv][lane] = z*z;
    } else {
      sh1[wv][lane] = 0.f; sh2[wv][lane] = 0.f;
    }
    __syncthreads();
    if (t < 64) {
      float s1 = sh1[0][t] + sh1[1][t] + sh1[2][t] + sh1[3][t];
      float s2 = sh2[0][t] + sh2[1][t] + sh2[2][t] + sh2[3][t];
      int bucket = bid & 63;
      atomicAdd(&ws[BNSTB + bucket*256 + t], s1);            // bt=0 agent
      atomicAdd(&ws[BNSTB + bucket*256 + 64 + t], s2);
    }
  } else {
    int node = (bid - 4000)*4 + wv;
    float outv = 0.f;
    #pragma unroll
    for (int rr = 0; rr < 2; ++rr) {
      int r = rr ? 2 : 0;
      const int* rp = wsi + ROWP_I + r*RELSTRIDE;
      const int* es = wsi + ESRC_I + r*NE;
      const float* als = ws + selALS(r);
      const ushortT* h16 = (const ushortT*)(ws + selH(r));
      float ad = (ws + selALD(r))[node*4 + hh];
      outv += agg_rel(es, rp[node], rp[node+1], als, h16, ad, lane, hh, base);
    }
    float bavg = 0.5f*(convBias[(layer*4 + 0)*64 + lane] + convBias[(layer*4 + 2)*64 + lane]);
    float z = fmaxf(outv*0.125f + bavg, 0.f);
    ws[OTACC + (size_t)node*64 + lane] = z;
    sh1[wv][lane] = z; sh2[wv][lane] = z*z;
    __syncthreads();
    if (t < 64) {
      float s1 = sh1[0][t] + sh1[1][t] + sh1[2][t] + sh1[3][t];
      float s2 = sh2[0][t] + sh2[1][t] + sh2[2][t] + sh2[3][t];
      int bucket = bid & 63;
      atomicAdd(&ws[BNSTB + bucket*256 + 128 + t], s1);      // bt=1 track
      atomicAdd(&ws[BNSTB + bucket*256 + 192 + t], s2);
    }
  }
}

// ---------------- reduce 64 BN-stat buckets -> BNST; optionally zero critic buckets ----------------
__global__ __launch_bounds__(256) void k_bnred2(float* ws, int zero_cstb) {
  int t = threadIdx.x;
  float s = 0.f;
  #pragma unroll
  for (int b = 0; b < 64; ++b) s += ws[BNSTB + b*256 + t];
  ws[BNST + t] = s;
  if (zero_cstb) {
    for (int i = t; i < 24576; i += 256) ws[CSTB + i] = 0.f;
  }
}

// ---------------- tail: BN(layer2)+residual -> x, fused critic column stats ----------------
__global__ __launch_bounds__(256) void k_bncrit(const float* bnG, const float* bnB, float* ws) {
  int bid = blockIdx.x;
  int t = threadIdx.x;
  int type, i0;
  if (bid < 2000) { type = 0; i0 = bid*256; }
  else            { type = 1; i0 = (bid-2000)*256; }
  float* acc = ws + (type ? OTACC : OAACC);
  float* x = ws + (type ? XT_OFF : XA_OFF);
  int i = i0 + t;
  int c = i & 63;
  float Nf = type ? 30000.f : 8000.f;
  float s1 = ws[BNST + type*128 + c], s2 = ws[BNST + type*128 + 64 + c];
  float mu = s1/Nf, var = s2/Nf - mu*mu;
  float g = bnG[(2*2+type)*64 + c], b = bnB[(2*2+type)*64 + c];
  float y = g*(acc[i]-mu)*rsqrtf(var+1e-5f) + b + x[i];
  x[i] = y;
  __shared__ float sd[3][256];
  sd[0][t] = y; sd[1][t] = y*y; sd[2][t] = y;
  __syncthreads();
  if (t < 64) {
    float a1 = sd[0][t]+sd[0][t+64]+sd[0][t+128]+sd[0][t+192];
    float a2 = sd[1][t]+sd[1][t+64]+sd[1][t+128]+sd[1][t+192];
    float mx = fmaxf(fmaxf(sd[2][t],sd[2][t+64]), fmaxf(sd[2][t+128],sd[2][t+192]));
    int bucket = bid & 63;
    atomicAdd(&ws[CSTB + bucket*384 + type*192 + t], a1);
    atomicAdd(&ws[CSTB + bucket*384 + type*192 + 64 + t], a2);
    atomicMax((unsigned*)&ws[CSTB + bucket*384 + type*192 + 128 + t], fmap(mx));
  }
}

// ---------------- actor heads: wave per node, both heads in parallel, flattened ----------------
__global__ __launch_bounds__(256) void k_actor(const float* aW1, const float* ab1, const float* ag,
    const float* abe, const float* aW2, const float* ab2, const float* ws, float* out) {
  int bid = blockIdx.x;
  int type, nb;
  if (bid < 2000) { type = 0; nb = bid; } else { type = 1; nb = bid - 2000; }
  int t = threadIdx.x, wv = t >> 6, lane = t & 63;
  int p = lane >> 5, j = lane & 31;
  int n = nb*4 + wv;
  const float* xg = ws + (type ? XT_OFF : XA_OFF);
  __shared__ float xsh[4][64];
  xsh[wv][lane] = xg[(size_t)n*64 + lane];
  __syncthreads();
  int i = (type ? 2 : 0) + p;
  const float* W = aW1 + i*2048 + j;
  float a0 = 0.f, a1 = 0.f, a2 = 0.f, a3 = 0.f;
  #pragma unroll
  for (int k = 0; k < 64; k += 4) {
    a0 += xsh[wv][k]   * W[k*32];
    a1 += xsh[wv][k+1] * W[(k+1)*32];
    a2 += xsh[wv][k+2] * W[(k+2)*32];
    a3 += xsh[wv][k+3] * W[(k+3)*32];
  }
  float tv = ((a0+a1)+(a2+a3)) + ab1[i*32 + j];
  float mu = wred32(tv) * (1.f/32.f);
  float dz = tv - mu;
  float var = wred32(dz*dz) * (1.f/32.f);
  float hn = fmaxf(ag[i*32+j]*dz*rsqrtf(var + 1e-5f) + abe[i*32+j], 0.f);
  float s = wred32(hn * aW2[i*32 + j]) + ab2[i];
  float val = softplusf(s) + 1.f;
  float vA = __shfl(val, 0);
  float vB = __shfl(val, 32);
  if (lane == 0) {
    int offA = type ? 24000 : 0, offB = type ? 54000 : 8000, offC = type ? 84000 : 16000;
    out[offA + n] = vA;
    out[offB + n] = vB;
    out[offC + n] = vA / (vA + vB);
  }
}

__device__ __forceinline__ float blocksum128(float v, float* red) {
  int t = threadIdx.x;
  red[t] = v; __syncthreads();
  #pragma unroll
  for (int s = 64; s > 0; s >>= 1) { if (t < s) red[t] += red[t+s]; __syncthreads(); }
  float r = red[0]; __syncthreads();
  return r;
}

// ---------------- critic MLP (reduces CSTB buckets in prologue) ----------------
__global__ __launch_bounds__(128) void k_critic(const float* cW1,const float* cb1,const float* cg1,const float* cbe1,
    const float* cW2,const float* cb2,const float* cg2,const float* cbe2,
    const float* cW3,const float* cb3,const float* cW4,const float* cb4,
    const float* ws, float* out) {
  __shared__ float g[384];
  __shared__ float h1[128];
  __shared__ float h2s[64];
  __shared__ float red[128];
  int t = threadIdx.x;
  if (t < 64) {
    #pragma unroll
    for (int type = 0; type < 2; ++type) {
      float s1 = 0.f, s2 = 0.f;
      unsigned mu_ = 0u;
      for (int b2 = 0; b2 < 64; ++b2) {
        s1 += ws[CSTB + b2*384 + type*192 + t];
        s2 += ws[CSTB + b2*384 + type*192 + 64 + t];
        unsigned u = __float_as_uint(ws[CSTB + b2*384 + type*192 + 128 + t]);
        mu_ = max(mu_, u);
      }
      float Nf = type ? 30000.f : 8000.f;
      float mean = s1 / Nf;
      float sd = sqrtf(fmaxf((s2 - Nf*mean*mean) / (Nf - 1.f), 0.f));
      g[type*192 + t] = mean;
      g[type*192 + 64 + t] = funmap(mu_);
      g[type*192 + 128 + t] = sd;
    }
  }
  __syncthreads();
  float v = cb1[t];
  for (int k = 0; k < 384; ++k) v += g[k] * cW1[k*128 + t];
  float mu = blocksum128(v, red) * (1.f/128.f);
  float d = v - mu;
  float var = blocksum128(d*d, red) * (1.f/128.f);
  h1[t] = fmaxf(cg1[t]*d*rsqrtf(var + 1e-5f) + cbe1[t], 0.f);
  __syncthreads();
  float v2 = 0.f;
  if (t < 64) { v2 = cb2[t]; for (int k = 0; k < 128; ++k) v2 += h1[k] * cW2[k*64 + t]; }
  float mu2 = blocksum128(t < 64 ? v2 : 0.f, red) * (1.f/64.f);
  float d2 = v2 - mu2;
  float var2 = blocksum128(t < 64 ? d2*d2 : 0.f, red) * (1.f/64.f);
  if (t < 64) h2s[t] = fmaxf(cg2[t]*d2*rsqrtf(var2 + 1e-5f) + cbe2[t], 0.f);
  __syncthreads();
  float v3 = 0.f;
  if (t < 32) {
    v3 = cb3[t];
    for (int k = 0; k < 64; ++k) v3 += h2s[k] * cW3[k*32 + t];
    v3 = fmaxf(v3, 0.f);
  }
  float s4 = blocksum128(t < 32 ? v3 * cW4[t] : 0.f, red);
  if (t == 0) out[114000] = s4 + cb4[0];
}

extern "C" void kernel_launch(void* const* d_in, const int* in_sizes, int n_in,
                              void* d_out, int out_size, void* d_ws, size_t ws_size,
                              hipStream_t stream) {
  const float* x_agent = (const float*)d_in[0];
  const float* x_track = (const float*)d_in[1];
  const int* s0 = (const int*)d_in[2]; const int* d0_ = (const int*)d_in[3];
  const int* s1 = (const int*)d_in[4]; const int* d1_ = (const int*)d_in[5];
  const int* s2 = (const int*)d_in[6]; const int* d2_ = (const int*)d_in[7];
  const int* s3 = (const int*)d_in[8]; const int* d3_ = (const int*)d_in[9];
  const float* aeW = (const float*)d_in[10]; const float* aeB = (const float*)d_in[11];
  const float* teW = (const float*)d_in[12]; const float* teB = (const float*)d_in[13];
  const float* convW    = (const float*)d_in[14];
  const float* convAsrc = (const float*)d_in[15];
  const float* convAdst = (const float*)d_in[16];
  const float* convBias = (const float*)d_in[17];
  const float* bnG = (const float*)d_in[18]; const float* bnB = (const float*)d_in[19];
  const float* aW1 = (const float*)d_in[20]; const float* ab1 = (const float*)d_in[21];
  const float* ag  = (const float*)d_in[22]; const float* abe = (const float*)d_in[23];
  const float* aW2 = (const float*)d_in[24]; const float* ab2 = (const float*)d_in[25];
  const float* cW1 = (const float*)d_in[26]; const float* cb1 = (const float*)d_in[27];
  const float* cg1 = (const float*)d_in[28]; const float* cbe1 = (const float*)d_in[29];
  const float* cW2 = (const float*)d_in[30]; const float* cb2 = (const float*)d_in[31];
  const float* cg2 = (const float*)d_in[32]; const float* cbe2 = (const float*)d_in[33];
  const float* cW3 = (const float*)d_in[34]; const float* cb3 = (const float*)d_in[35];
  const float* cW4 = (const float*)d_in[36]; const float* cb4 = (const float*)d_in[37];
  float* ws = (float*)d_ws;
  int* wsi = (int*)d_ws;
  float* out = (float*)d_out;

  hipMemsetAsync(wsi + ROWP_I, 0, (size_t)240128 * sizeof(int), stream);

  k_pre<<<dim3(11856), 256, 0, stream>>>(x_agent, x_track, aeW, aeB, teW, teB,
                                         d0_, d1_, d2_, d3_, convW, convAsrc, convAdst, ws);
  k_scan<<<dim3(4), 256, 0, stream>>>(wsi);
  k_fill<<<dim3(586, 4), 256, 0, stream>>>(s0,d0_,s1,d1_,s2,d2_,s3,d3_, wsi);

  for (int l = 0; l < 3; ++l) {
    int mode = (l == 0) ? 0 : (l == 1 ? 1 : 2);
    k_fusedA<<<dim3(2375), 256, 0, stream>>>(bnG, bnB, ws, l, mode);
    k_agg<<<dim3(11500), 256, 0, stream>>>(convBias, ws, l);
    k_bnred2<<<dim3(1), 256, 0, stream>>>(ws, l == 2 ? 1 : 0);
  }

  k_bncrit<<<dim3(9500), 256, 0, stream>>>(bnG, bnB, ws);
  k_actor<<<dim3(9500), 256, 0, stream>>>(aW1, ab1, ag, abe, aW2, ab2, ws, out);
  k_critic<<<1, 128, 0, stream>>>(cW1,cb1,cg1,cbe1,cW2,cb2,cg2,cbe2,cW3,cb3,cW4,cb4, ws, out);
}

// Round 15
// 652.975 us; speedup vs baseline: 1.4943x; 1.4943x over previous
//
#include <hip/hip_runtime.h>
#include <math.h>

#define NAg 8000
#define NTr 30000
#define NE  150000

// ---- workspace layout (float offsets) ----
#define XA_OFF 0          // 8000*64
#define XT_OFF 512000     // 30000*64
#define H0_OFF 2432000    // bf16 interleaved [node][c*4+h], 256 ushorts/node
#define H1_OFF 4480000
#define H2_OFF 12160000
#define H3_OFF 14208000   // bf16 ends at float 18048000
#define BNSTB 8320000     // 64 buckets x [2][128] = 16384 floats
#define WVB   8336384     // [layer][side*4+r][256] = 6144 floats
#define W2B   8342528     // [layer][r][64][256] fp32 interleaved = 196608 floats
#define CSTB  18100000    // 64 buckets x [type][192] = 24576 floats
#define ALS0 21888000
#define ALS1 21920000
#define ALS2 22040000
#define ALS3 22072000
#define ALD0 22192000
#define ALD1 22312000
#define ALD2 22344000
#define ALD3 22464000
#define ESRC_I 22496000   // int offsets into (int*)ws; 4 x 150000
#define OAACC 23104000    // 8000*64
#define OTACC 23616000    // 30000*64
#define BNST 25536000     // [type: 0 agent,1 track][2][64]
#define ROWP_I 25536640   // 4 x 30016 ints
#define CURS_I 25656704   // 4 x 30016 ints
#define RELSTRIDE 30016

typedef unsigned short ushortT;

__device__ __forceinline__ float lrelu(float x){ return x >= 0.f ? x : 0.2f*x; }
__device__ __forceinline__ unsigned fmap(float f){ unsigned u=__float_as_uint(f); return (u&0x80000000u)? ~u : (u|0x80000000u); }
__device__ __forceinline__ float funmap(unsigned u){ return (u&0x80000000u)? __uint_as_float(u&0x7FFFFFFFu) : __uint_as_float(~u); }
__device__ __forceinline__ float softplusf(float x){ return fmaxf(x,0.f) + log1pf(expf(-fabsf(x))); }
__device__ __forceinline__ ushortT f2bf(float f){
  unsigned u = __float_as_uint(f);
  unsigned r = u + 0x7FFFu + ((u>>16)&1u);   // RNE
  return (ushortT)(r>>16);
}
__device__ __forceinline__ float bf2f(ushortT s){ return __uint_as_float(((unsigned)s)<<16); }
__device__ __forceinline__ float wred64(float v){
  #pragma unroll
  for (int o=32;o;o>>=1) v += __shfl_xor(v,o);
  return v;
}
__device__ __forceinline__ float wred32(float v){
  #pragma unroll
  for (int o=16;o;o>>=1) v += __shfl_xor(v,o,32);
  return v;
}
__device__ __forceinline__ int selH(int r){ return r==0?H0_OFF: r==1?H1_OFF: r==2?H2_OFF:H3_OFF; }
__device__ __forceinline__ int selALS(int r){ return r==0?ALS0: r==1?ALS1: r==2?ALS2:ALS3; }
__device__ __forceinline__ int selALD(int r){ return r==0?ALD0: r==1?ALD1: r==2?ALD2:ALD3; }

// per-relation softmax-weighted aggregation for one node's edge list (shuffle version)
__device__ __forceinline__ float agg_rel(const int* es, int p, int p1, const float* als,
                                         const ushortT* h16, float ad, int lane, int hh, int base) {
  float num0=0.f, num1=0.f, num2=0.f, num3=0.f, den=0.f;
  for (; p + 4 <= p1; p += 4) {
    int sa = es[p], sb = es[p+1], sc = es[p+2], sd4 = es[p+3];
    ushort4 va = *(const ushort4*)(h16 + (size_t)sa*256 + lane*4);
    ushort4 vb = *(const ushort4*)(h16 + (size_t)sb*256 + lane*4);
    ushort4 vc = *(const ushort4*)(h16 + (size_t)sc*256 + lane*4);
    ushort4 vd = *(const ushort4*)(h16 + (size_t)sd4*256 + lane*4);
    float la = als[sa*4+hh], lb = als[sb*4+hh], lc = als[sc*4+hh], ld = als[sd4*4+hh];
    float ea = __expf(lrelu(la + ad));
    float eb = __expf(lrelu(lb + ad));
    float ec = __expf(lrelu(lc + ad));
    float ed = __expf(lrelu(ld + ad));
    den += (ea+eb)+(ec+ed);
    float qa0=__shfl(ea,base), qa1=__shfl(ea,base+1), qa2=__shfl(ea,base+2), qa3=__shfl(ea,base+3);
    float qb0=__shfl(eb,base), qb1=__shfl(eb,base+1), qb2=__shfl(eb,base+2), qb3=__shfl(eb,base+3);
    float qc0=__shfl(ec,base), qc1=__shfl(ec,base+1), qc2=__shfl(ec,base+2), qc3=__shfl(ec,base+3);
    float qd0=__shfl(ed,base), qd1=__shfl(ed,base+1), qd2=__shfl(ed,base+2), qd3=__shfl(ed,base+3);
    num0 += qa0*bf2f(va.x) + qb0*bf2f(vb.x) + qc0*bf2f(vc.x) + qd0*bf2f(vd.x);
    num1 += qa1*bf2f(va.y) + qb1*bf2f(vb.y) + qc1*bf2f(vc.y) + qd1*bf2f(vd.y);
    num2 += qa2*bf2f(va.z) + qb2*bf2f(vb.z) + qc2*bf2f(vc.z) + qd2*bf2f(vd.z);
    num3 += qa3*bf2f(va.w) + qb3*bf2f(vb.w) + qc3*bf2f(vc.w) + qd3*bf2f(vd.w);
  }
  for (; p < p1; ++p) {
    int s = es[p];
    ushort4 va = *(const ushort4*)(h16 + (size_t)s*256 + lane*4);
    float e = __expf(lrelu(als[s*4 + hh] + ad));
    den += e;
    float q0 = __shfl(e, base), q1 = __shfl(e, base+1), q2 = __shfl(e, base+2), q3 = __shfl(e, base+3);
    num0 += q0*bf2f(va.x); num1 += q1*bf2f(va.y); num2 += q2*bf2f(va.z); num3 += q3*bf2f(va.w);
  }
  float rd = 1.f/(den + 1e-16f);
  float r0 = __shfl(rd, base), r1 = __shfl(rd, base+1), r2 = __shfl(rd, base+2), r3 = __shfl(rd, base+3);
  return num0*r0 + num1*r1 + num2*r2 + num3*r3;
}

// ---------------- pre: encoder + CSR histogram + weight prep, one kernel ----------------
__global__ __launch_bounds__(256) void k_pre(const float* xA, const float* xT,
    const float* aeW, const float* aeB, const float* teW, const float* teB,
    const int* d0_, const int* d1_, const int* d2_, const int* d3_,
    const float* convW, const float* convAsrc, const float* convAdst, float* ws) {
  int bid = blockIdx.x;
  int t = threadIdx.x;
  __shared__ float xs[4][48];
  if (bid < 9500) {
    int wv = t >> 6, lane = t & 63;
    int type, nb;
    if (bid < 2000) { type = 0; nb = bid; } else { type = 1; nb = bid - 2000; }
    int n = nb*4 + wv;
    int F = type ? 48 : 32;
    const float* X = type ? xT : xA;
    const float* W = type ? teW : aeW;
    const float* B = type ? teB : aeB;
    float* out = ws + (type ? XT_OFF : XA_OFF);
    if (lane < F) xs[wv][lane] = X[(size_t)n*F + lane];
    __syncthreads();
    float acc = B[lane];
    for (int k = 0; k < F; ++k) acc += xs[wv][k] * W[k*64 + lane];
    out[(size_t)n*64 + lane] = fmaxf(acc, 0.f);
  } else if (bid < 11844) {
    int idx = bid - 9500;
    int r = idx / 586, eb = idx % 586;
    const int* dp = r==0? d0_ : r==1? d1_ : r==2? d2_ : d3_;
    int e = eb*256 + t;
    if (e < NE) atomicAdd(&((int*)ws)[ROWP_I + r*RELSTRIDE + dp[e]], 1);
  } else {
    int lr = bid - 11844;            // layer*4 + r
    int layer = lr >> 2, r = lr & 3;
    const float* W = convW + (size_t)lr*64*256;
    float* W2 = ws + W2B + (size_t)lr*64*256;
    int c = t >> 2, h = t & 3;
    for (int k = 0; k < 64; ++k) W2[k*256 + t] = W[k*256 + h*64 + c];
    int k = t >> 2;
    const float* ad = convAdst + (size_t)lr*256;
    const float* as = convAsrc + (size_t)lr*256;
    float s0 = 0.f, s1 = 0.f;
    for (int cc = 0; cc < 64; ++cc) {
      float w = W[k*256 + h*64 + cc];
      s0 += w * ad[h*64 + cc];
      s1 += w * as[h*64 + cc];
    }
    ws[WVB + (size_t)(layer*8 + 0*4 + r)*256 + t] = s0;   // side 0: ald
    ws[WVB + (size_t)(layer*8 + 1*4 + r)*256 + t] = s1;   // side 1: als
  }
}

// ---------------- CSR build: exclusive scan per relation ----------------
__global__ __launch_bounds__(256) void k_scan(int* wsi) {
  int r = blockIdx.x;
  int n = ((r & 1) ? NAg : NTr) + 1;
  int* rp = wsi + ROWP_I + r*RELSTRIDE;
  __shared__ int part[256];
  int t = threadIdx.x;
  int chunk = (n + 255) / 256;
  int lo = t*chunk, hi = min(lo + chunk, n);
  int s = 0;
  for (int i = lo; i < hi; ++i) s += rp[i];
  part[t] = s;
  __syncthreads();
  if (t == 0) {
    int run = 0;
    for (int i = 0; i < 256; ++i) { int tm = part[i]; part[i] = run; run += tm; }
  }
  __syncthreads();
  int run = part[t];
  for (int i = lo; i < hi; ++i) { int tm = rp[i]; rp[i] = run; run += tm; }
}

// ---------------- CSR build: fill sorted src lists ----------------
__global__ __launch_bounds__(256) void k_fill(const int* s0,const int* d0_,const int* s1,const int* d1_,
    const int* s2,const int* d2_,const int* s3,const int* d3_, int* wsi) {
  int r = blockIdx.y;
  const int* sp = r==0? s0 : r==1? s1 : r==2? s2 : s3;
  const int* dp = r==0? d0_ : r==1? d1_ : r==2? d2_ : d3_;
  int e = blockIdx.x*256 + threadIdx.x;
  if (e >= NE) return;
  int d = dp[e];
  int pos = wsi[ROWP_I + r*RELSTRIDE + d] + atomicAdd(&wsi[CURS_I + r*RELSTRIDE + d], 1);
  wsi[ESRC_I + r*NE + pos] = sp[e];
}

// ---------------- alpha logits: wave per node, coalesced; zeroes BNSTB ----------------
__global__ __launch_bounds__(256) void k_alx(float* ws, int layer) {
  int bid = blockIdx.x;
  int t = threadIdx.x;
  if (bid < 64) ws[BNSTB + bid*256 + t] = 0.f;
  int y, b0;
  if (bid < 7500)       { y = 0; b0 = bid; }
  else if (bid < 9500)  { y = 1; b0 = bid - 7500; }
  else if (bid < 17000) { y = 2; b0 = bid - 9500; }
  else if (bid < 19000) { y = 3; b0 = bid - 17000; }
  else if (bid < 21000) { y = 4; b0 = bid - 19000; }
  else if (bid < 28500) { y = 5; b0 = bid - 21000; }
  else if (bid < 30500) { y = 6; b0 = bid - 28500; }
  else                  { y = 7; b0 = bid - 30500; }
  int side = y >> 2, r = y & 3;
  int wv = t >> 6, lane = t & 63;
  int n = b0*4 + wv;
  const float* xv = ws + (side ? ((r & 1) ? XT_OFF : XA_OFF) : ((r & 1) ? XA_OFF : XT_OFF));
  float4 wv4 = *(const float4*)(ws + WVB + (size_t)(layer*8 + y)*256 + lane*4);
  float xk = xv[(size_t)n*64 + lane];
  float p0 = wred64(xk * wv4.x);
  float p1 = wred64(xk * wv4.y);
  float p2 = wred64(xk * wv4.z);
  float p3 = wred64(xk * wv4.w);
  if (lane == 0) {
    float4 o; o.x = p0; o.y = p1; o.z = p2; o.w = p3;
    *(float4*)(ws + (side ? selALS(r) : selALD(r)) + (size_t)n*4) = o;
  }
}

// ---------------- h = x_src @ W2 (bf16 interleaved store), flattened grid ----------------
__global__ __launch_bounds__(256) void k_hgemm(float* ws, int layer) {
  int tile = blockIdx.x;          // 4750 tiles: r0:500, r1:1875, r2:500, r3:1875
  int r, row0;
  if (tile < 500)        { r = 0; row0 = tile*16; }
  else if (tile < 2375)  { r = 1; row0 = (tile-500)*16; }
  else if (tile < 2875)  { r = 2; row0 = (tile-2375)*16; }
  else                   { r = 3; row0 = (tile-2875)*16; }
  const float* W2 = ws + W2B + (size_t)(layer*4 + r)*64*256;
  const float* xg = ws + ((r & 1) ? XT_OFF : XA_OFF);
  ushortT* h16 = (ushortT*)(ws + selH(r));
  __shared__ float xs[16][64];
  int t = threadIdx.x;
  #pragma unroll
  for (int i = 0; i < 4; ++i) {
    int lin = i*256 + t;
    xs[lin>>6][lin&63] = xg[((size_t)row0 + (lin>>6))*64 + (lin&63)];
  }
  __syncthreads();
  int c0 = t & 63;
  int tr = t >> 6;
  float acc[4][4];
  #pragma unroll
  for (int i=0;i<4;i++){ acc[i][0]=0;acc[i][1]=0;acc[i][2]=0;acc[i][3]=0; }
  const float* Wc = W2 + c0*4;
  for (int k4 = 0; k4 < 16; ++k4) {
    float4 xv[4];
    #pragma unroll
    for (int i = 0; i < 4; ++i) xv[i] = *(const float4*)&xs[tr*4+i][k4*4];
    #pragma unroll
    for (int kk = 0; kk < 4; ++kk) {
      int k = k4*4 + kk;
      float4 w4 = *(const float4*)(Wc + k*256);
      #pragma unroll
      for (int i = 0; i < 4; ++i) {
        float x = (kk==0)?xv[i].x:(kk==1)?xv[i].y:(kk==2)?xv[i].z:xv[i].w;
        acc[i][0] += x*w4.x; acc[i][1] += x*w4.y; acc[i][2] += x*w4.z; acc[i][3] += x*w4.w;
      }
    }
  }
  #pragma unroll
  for (int i = 0; i < 4; ++i) {
    int row = row0 + tr*4 + i;
    ushort4 pk;
    pk.x = f2bf(acc[i][0]); pk.y = f2bf(acc[i][1]);
    pk.z = f2bf(acc[i][2]); pk.w = f2bf(acc[i][3]);
    *(ushort4*)(h16 + (size_t)row*256 + c0*4) = pk;
  }
}

// ---------------- fused CSR aggregation, flattened grid, agents-first ----------------
__global__ __launch_bounds__(256) void k_agg(const float* convBias, float* ws, int layer) {
  int t = threadIdx.x, wv = t >> 6, lane = t & 63, hh = lane & 3, base = lane & ~3;
  const int* wsi = (const int*)ws;
  int bid = blockIdx.x;
  __shared__ float part[4][64];
  __shared__ float sh1[4][64];
  __shared__ float sh2[4][64];
  if (bid < 4000) {
    int node = bid*2 + (wv >> 1);
    int rr = wv & 1;
    int r = rr ? 3 : 1;
    const int* rp = wsi + ROWP_I + r*RELSTRIDE;
    const int* es = wsi + ESRC_I + r*NE;
    const float* als = ws + selALS(r);
    const ushortT* h16 = (const ushortT*)(ws + selH(r));
    float ad = (ws + selALD(r))[node*4 + hh];
    part[wv][lane] = agg_rel(es, rp[node], rp[node+1], als, h16, ad, lane, hh, base);
    __syncthreads();
    if (rr == 0) {
      float o = part[wv][lane] + part[wv+1][lane];
      float bavg = 0.5f*(convBias[(layer*4 + 1)*64 + lane] + convBias[(layer*4 + 3)*64 + lane]);
      float z = fmaxf(o*0.125f + bavg, 0.f);
      ws[OAACC + (size_t)node*64 + lane] = z;
      sh1[wv][lane] = z; sh2[wv][lane] = z*z;
    } else {
      sh1[wv][lane] = 0.f; sh2[wv][lane] = 0.f;
    }
    __syncthreads();
    if (t < 64) {
      float s1 = sh1[0][t] + sh1[1][t] + sh1[2][t] + sh1[3][t];
      float s2 = sh2[0][t] + sh2[1][t] + sh2[2][t] + sh2[3][t];
      int bucket = bid & 63;
      atomicAdd(&ws[BNSTB + bucket*256 + t], s1);            // bt=0 agent
      atomicAdd(&ws[BNSTB + bucket*256 + 64 + t], s2);
    }
  } else {
    int node = (bid - 4000)*4 + wv;
    float outv = 0.f;
    #pragma unroll
    for (int rr = 0; rr < 2; ++rr) {
      int r = rr ? 2 : 0;
      const int* rp = wsi + ROWP_I + r*RELSTRIDE;
      const int* es = wsi + ESRC_I + r*NE;
      const float* als = ws + selALS(r);
      const ushortT* h16 = (const ushortT*)(ws + selH(r));
      float ad = (ws + selALD(r))[node*4 + hh];
      outv += agg_rel(es, rp[node], rp[node+1], als, h16, ad, lane, hh, base);
    }
    float bavg = 0.5f*(convBias[(layer*4 + 0)*64 + lane] + convBias[(layer*4 + 2)*64 + lane]);
    float z = fmaxf(outv*0.125f + bavg, 0.f);
    ws[OTACC + (size_t)node*64 + lane] = z;
    sh1[wv][lane] = z; sh2[wv][lane] = z*z;
    __syncthreads();
    if (t < 64) {
      float s1 = sh1[0][t] + sh1[1][t] + sh1[2][t] + sh1[3][t];
      float s2 = sh2[0][t] + sh2[1][t] + sh2[2][t] + sh2[3][t];
      int bucket = bid & 63;
      atomicAdd(&ws[BNSTB + bucket*256 + 128 + t], s1);      // bt=1 track
      atomicAdd(&ws[BNSTB + bucket*256 + 192 + t], s2);
    }
  }
}

// ---------------- reduce 64 BN-stat buckets -> BNST; optionally zero critic buckets ----------------
__global__ __launch_bounds__(256) void k_bnred2(float* ws, int zero_cstb) {
  int t = threadIdx.x;
  float s = 0.f;
  #pragma unroll
  for (int b = 0; b < 64; ++b) s += ws[BNSTB + b*256 + t];
  ws[BNST + t] = s;
  if (zero_cstb) {
    for (int i = t; i < 24576; i += 256) ws[CSTB + i] = 0.f;
  }
}

// ---------------- batchnorm + residual, flattened grid (layers 0,1) ----------------
__global__ __launch_bounds__(256) void k_bnnorm(const float* bnG, const float* bnB, float* ws, int layer) {
  int bid = blockIdx.x;
  int type, i;
  if (bid < 2000) { type = 0; i = bid*256 + threadIdx.x; }
  else            { type = 1; i = (bid - 2000)*256 + threadIdx.x; }
  float* acc = ws + (type ? OTACC : OAACC);
  float* x = ws + (type ? XT_OFF : XA_OFF);
  int c = i & 63;
  float Nf = type ? 30000.f : 8000.f;
  float s1 = ws[BNST + type*128 + c], s2 = ws[BNST + type*128 + 64 + c];
  float mu = s1/Nf, var = s2/Nf - mu*mu;
  float g = bnG[(layer*2 + type)*64 + c], b = bnB[(layer*2 + type)*64 + c];
  float y = g*(acc[i]-mu)*rsqrtf(var + 1e-5f) + b;
  if (layer > 0) y += x[i];
  x[i] = y;
}

// ---------------- tail: BN(layer2)+residual -> x, fused bucketed critic stats ----------------
__global__ __launch_bounds__(256) void k_bncrit(const float* bnG, const float* bnB, float* ws) {
  int bid = blockIdx.x;
  int t = threadIdx.x;
  int type, i0;
  if (bid < 2000) { type = 0; i0 = bid*256; }
  else            { type = 1; i0 = (bid-2000)*256; }
  float* acc = ws + (type ? OTACC : OAACC);
  float* x = ws + (type ? XT_OFF : XA_OFF);
  int i = i0 + t;
  int c = i & 63;
  float Nf = type ? 30000.f : 8000.f;
  float s1 = ws[BNST + type*128 + c], s2 = ws[BNST + type*128 + 64 + c];
  float mu = s1/Nf, var = s2/Nf - mu*mu;
  float g = bnG[(2*2+type)*64 + c], b = bnB[(2*2+type)*64 + c];
  float y = g*(acc[i]-mu)*rsqrtf(var+1e-5f) + b + x[i];
  x[i] = y;
  __shared__ float sd[3][256];
  sd[0][t] = y; sd[1][t] = y*y; sd[2][t] = y;
  __syncthreads();
  if (t < 64) {
    float a1 = sd[0][t]+sd[0][t+64]+sd[0][t+128]+sd[0][t+192];
    float a2 = sd[1][t]+sd[1][t+64]+sd[1][t+128]+sd[1][t+192];
    float mx = fmaxf(fmaxf(sd[2][t],sd[2][t+64]), fmaxf(sd[2][t+128],sd[2][t+192]));
    int bucket = bid & 63;
    atomicAdd(&ws[CSTB + bucket*384 + type*192 + t], a1);
    atomicAdd(&ws[CSTB + bucket*384 + type*192 + 64 + t], a2);
    atomicMax((unsigned*)&ws[CSTB + bucket*384 + type*192 + 128 + t], fmap(mx));
  }
}

// ---------------- actor heads: wave per node, both heads in parallel, flattened ----------------
__global__ __launch_bounds__(256) void k_actor(const float* aW1, const float* ab1, const float* ag,
    const float* abe, const float* aW2, const float* ab2, const float* ws, float* out) {
  int bid = blockIdx.x;
  int type, nb;
  if (bid < 2000) { type = 0; nb = bid; } else { type = 1; nb = bid - 2000; }
  int t = threadIdx.x, wv = t >> 6, lane = t & 63;
  int p = lane >> 5, j = lane & 31;
  int n = nb*4 + wv;
  const float* xg = ws + (type ? XT_OFF : XA_OFF);
  __shared__ float xsh[4][64];
  xsh[wv][lane] = xg[(size_t)n*64 + lane];
  __syncthreads();
  int i = (type ? 2 : 0) + p;
  const float* W = aW1 + i*2048 + j;
  float a0 = 0.f, a1 = 0.f, a2 = 0.f, a3 = 0.f;
  #pragma unroll
  for (int k = 0; k < 64; k += 4) {
    a0 += xsh[wv][k]   * W[k*32];
    a1 += xsh[wv][k+1] * W[(k+1)*32];
    a2 += xsh[wv][k+2] * W[(k+2)*32];
    a3 += xsh[wv][k+3] * W[(k+3)*32];
  }
  float tv = ((a0+a1)+(a2+a3)) + ab1[i*32 + j];
  float mu = wred32(tv) * (1.f/32.f);
  float dz = tv - mu;
  float var = wred32(dz*dz) * (1.f/32.f);
  float hn = fmaxf(ag[i*32+j]*dz*rsqrtf(var + 1e-5f) + abe[i*32+j], 0.f);
  float s = wred32(hn * aW2[i*32 + j]) + ab2[i];
  float val = softplusf(s) + 1.f;
  float vA = __shfl(val, 0);
  float vB = __shfl(val, 32);
  if (lane == 0) {
    int offA = type ? 24000 : 0, offB = type ? 54000 : 8000, offC = type ? 84000 : 16000;
    out[offA + n] = vA;
    out[offB + n] = vB;
    out[offC + n] = vA / (vA + vB);
  }
}

__device__ __forceinline__ float blocksum128(float v, float* red) {
  int t = threadIdx.x;
  red[t] = v; __syncthreads();
  #pragma unroll
  for (int s = 64; s > 0; s >>= 1) { if (t < s) red[t] += red[t+s]; __syncthreads(); }
  float r = red[0]; __syncthreads();
  return r;
}

// ---------------- critic MLP (reduces CSTB buckets in prologue) ----------------
__global__ __launch_bounds__(128) void k_critic(const float* cW1,const float* cb1,const float* cg1,const float* cbe1,
    const float* cW2,const float* cb2,const float* cg2,const float* cbe2,
    const float* cW3,const float* cb3,const float* cW4,const float* cb4,
    const float* ws, float* out) {
  __shared__ float g[384];
  __shared__ float h1[128];
  __shared__ float h2s[64];
  __shared__ float red[128];
  int t = threadIdx.x;
  if (t < 64) {
    #pragma unroll
    for (int type = 0; type < 2; ++type) {
      float s1 = 0.f, s2 = 0.f;
      unsigned mu_ = 0u;
      for (int b2 = 0; b2 < 64; ++b2) {
        s1 += ws[CSTB + b2*384 + type*192 + t];
        s2 += ws[CSTB + b2*384 + type*192 + 64 + t];
        unsigned u = __float_as_uint(ws[CSTB + b2*384 + type*192 + 128 + t]);
        mu_ = max(mu_, u);
      }
      float Nf = type ? 30000.f : 8000.f;
      float mean = s1 / Nf;
      float sd = sqrtf(fmaxf((s2 - Nf*mean*mean) / (Nf - 1.f), 0.f));
      g[type*192 + t] = mean;
      g[type*192 + 64 + t] = funmap(mu_);
      g[type*192 + 128 + t] = sd;
    }
  }
  __syncthreads();
  float v = cb1[t];
  for (int k = 0; k < 384; ++k) v += g[k] * cW1[k*128 + t];
  float mu = blocksum128(v, red) * (1.f/128.f);
  float d = v - mu;
  float var = blocksum128(d*d, red) * (1.f/128.f);
  h1[t] = fmaxf(cg1[t]*d*rsqrtf(var + 1e-5f) + cbe1[t], 0.f);
  __syncthreads();
  float v2 = 0.f;
  if (t < 64) { v2 = cb2[t]; for (int k = 0; k < 128; ++k) v2 += h1[k] * cW2[k*64 + t]; }
  float mu2 = blocksum128(t < 64 ? v2 : 0.f, red) * (1.f/64.f);
  float d2 = v2 - mu2;
  float var2 = blocksum128(t < 64 ? d2*d2 : 0.f, red) * (1.f/64.f);
  if (t < 64) h2s[t] = fmaxf(cg2[t]*d2*rsqrtf(var2 + 1e-5f) + cbe2[t], 0.f);
  __syncthreads();
  float v3 = 0.f;
  if (t < 32) {
    v3 = cb3[t];
    for (int k = 0; k < 64; ++k) v3 += h2s[k] * cW3[k*32 + t];
    v3 = fmaxf(v3, 0.f);
  }
  float s4 = blocksum128(t < 32 ? v3 * cW4[t] : 0.f, red);
  if (t == 0) out[114000] = s4 + cb4[0];
}

extern "C" void kernel_launch(void* const* d_in, const int* in_sizes, int n_in,
                              void* d_out, int out_size, void* d_ws, size_t ws_size,
                              hipStream_t stream) {
  const float* x_agent = (const float*)d_in[0];
  const float* x_track = (const float*)d_in[1];
  const int* s0 = (const int*)d_in[2]; const int* d0_ = (const int*)d_in[3];
  const int* s1 = (const int*)d_in[4]; const int* d1_ = (const int*)d_in[5];
  const int* s2 = (const int*)d_in[6]; const int* d2_ = (const int*)d_in[7];
  const int* s3 = (const int*)d_in[8]; const int* d3_ = (const int*)d_in[9];
  const float* aeW = (const float*)d_in[10]; const float* aeB = (const float*)d_in[11];
  const float* teW = (const float*)d_in[12]; const float* teB = (const float*)d_in[13];
  const float* convW    = (const float*)d_in[14];
  const float* convAsrc = (const float*)d_in[15];
  const float* convAdst = (const float*)d_in[16];
  const float* convBias = (const float*)d_in[17];
  const float* bnG = (const float*)d_in[18]; const float* bnB = (const float*)d_in[19];
  const float* aW1 = (const float*)d_in[20]; const float* ab1 = (const float*)d_in[21];
  const float* ag  = (const float*)d_in[22]; const float* abe = (const float*)d_in[23];
  const float* aW2 = (const float*)d_in[24]; const float* ab2 = (const float*)d_in[25];
  const float* cW1 = (const float*)d_in[26]; const float* cb1 = (const float*)d_in[27];
  const float* cg1 = (const float*)d_in[28]; const float* cbe1 = (const float*)d_in[29];
  const float* cW2 = (const float*)d_in[30]; const float* cb2 = (const float*)d_in[31];
  const float* cg2 = (const float*)d_in[32]; const float* cbe2 = (const float*)d_in[33];
  const float* cW3 = (const float*)d_in[34]; const float* cb3 = (const float*)d_in[35];
  const float* cW4 = (const float*)d_in[36]; const float* cb4 = (const float*)d_in[37];
  float* ws = (float*)d_ws;
  int* wsi = (int*)d_ws;
  float* out = (float*)d_out;

  hipMemsetAsync(wsi + ROWP_I, 0, (size_t)240128 * sizeof(int), stream);

  k_pre<<<dim3(11856), 256, 0, stream>>>(x_agent, x_track, aeW, aeB, teW, teB,
                                         d0_, d1_, d2_, d3_, convW, convAsrc, convAdst, ws);
  k_scan<<<dim3(4), 256, 0, stream>>>(wsi);
  k_fill<<<dim3(586, 4), 256, 0, stream>>>(s0,d0_,s1,d1_,s2,d2_,s3,d3_, wsi);

  for (int l = 0; l < 3; ++l) {
    k_alx<<<dim3(38000), 256, 0, stream>>>(ws, l);
    k_hgemm<<<dim3(4750), 256, 0, stream>>>(ws, l);
    k_agg<<<dim3(11500), 256, 0, stream>>>(convBias, ws, l);
    k_bnred2<<<dim3(1), 256, 0, stream>>>(ws, l == 2 ? 1 : 0);
    if (l < 2) k_bnnorm<<<dim3(9500), 256, 0, stream>>>(bnG, bnB, ws, l);
  }

  k_bncrit<<<dim3(9500), 256, 0, stream>>>(bnG, bnB, ws);
  k_actor<<<dim3(9500), 256, 0, stream>>>(aW1, ab1, ag, abe, aW2, ab2, ws, out);
  k_critic<<<1, 128, 0, stream>>>(cW1,cb1,cg1,cbe1,cW2,cb2,cg2,cbe2,cW3,cb3,cW4,cb4, ws, out);
}

// Round 16
// 652.574 us; speedup vs baseline: 1.4952x; 1.0006x over previous
//
#include <hip/hip_runtime.h>
#include <math.h>

#define NAg 8000
#define NTr 30000
#define NE  150000

// ---- workspace layout (float offsets) ----
#define XA_OFF 0          // 8000*64
#define XT_OFF 512000     // 30000*64
#define H0_OFF 2432000    // bf16 interleaved [node][c*4+h], 256 ushorts/node
#define H1_OFF 4480000
#define H2_OFF 12160000
#define H3_OFF 14208000   // bf16 ends at float 18048000
#define BNSTB 8320000     // 64 buckets x [2][128] = 16384 floats
#define WVB   8336384     // [layer][side*4+r][256] = 6144 floats
#define W2B   8342528     // [layer][r][64][256] fp32 interleaved = 196608 floats
#define CSTB  18100000    // 64 buckets x [type][192] = 24576 floats
#define ALS0 21888000
#define ALS1 21920000
#define ALS2 22040000
#define ALS3 22072000
#define ALD0 22192000
#define ALD1 22312000
#define ALD2 22344000
#define ALD3 22464000
#define ESRC_I 22496000   // int offsets into (int*)ws; 4 x 150000
#define OAACC 23104000    // 8000*64
#define OTACC 23616000    // 30000*64
#define BNST 25536000     // [type: 0 agent,1 track][2][64]
#define ROWP_I 25536640   // 4 x 30016 ints
#define CURS_I 25656704   // 4 x 30016 ints
#define RELSTRIDE 30016

typedef unsigned short ushortT;

__device__ __forceinline__ float lrelu(float x){ return x >= 0.f ? x : 0.2f*x; }
__device__ __forceinline__ unsigned fmap(float f){ unsigned u=__float_as_uint(f); return (u&0x80000000u)? ~u : (u|0x80000000u); }
__device__ __forceinline__ float funmap(unsigned u){ return (u&0x80000000u)? __uint_as_float(u&0x7FFFFFFFu) : __uint_as_float(~u); }
__device__ __forceinline__ float softplusf(float x){ return fmaxf(x,0.f) + log1pf(expf(-fabsf(x))); }
__device__ __forceinline__ ushortT f2bf(float f){
  unsigned u = __float_as_uint(f);
  unsigned r = u + 0x7FFFu + ((u>>16)&1u);   // RNE
  return (ushortT)(r>>16);
}
__device__ __forceinline__ float bf2f(ushortT s){ return __uint_as_float(((unsigned)s)<<16); }
__device__ __forceinline__ float wred64(float v){
  #pragma unroll
  for (int o=32;o;o>>=1) v += __shfl_xor(v,o);
  return v;
}
__device__ __forceinline__ float wred32(float v){
  #pragma unroll
  for (int o=16;o;o>>=1) v += __shfl_xor(v,o,32);
  return v;
}
__device__ __forceinline__ int selH(int r){ return r==0?H0_OFF: r==1?H1_OFF: r==2?H2_OFF:H3_OFF; }
__device__ __forceinline__ int selALS(int r){ return r==0?ALS0: r==1?ALS1: r==2?ALS2:ALS3; }
__device__ __forceinline__ int selALD(int r){ return r==0?ALD0: r==1?ALD1: r==2?ALD2:ALD3; }

// per-relation softmax-weighted aggregation for one node's edge list (shuffle version)
__device__ __forceinline__ float agg_rel(const int* es, int p, int p1, const float* als,
                                         const ushortT* h16, float ad, int lane, int hh, int base) {
  float num0=0.f, num1=0.f, num2=0.f, num3=0.f, den=0.f;
  for (; p + 4 <= p1; p += 4) {
    int sa = es[p], sb = es[p+1], sc = es[p+2], sd4 = es[p+3];
    ushort4 va = *(const ushort4*)(h16 + (size_t)sa*256 + lane*4);
    ushort4 vb = *(const ushort4*)(h16 + (size_t)sb*256 + lane*4);
    ushort4 vc = *(const ushort4*)(h16 + (size_t)sc*256 + lane*4);
    ushort4 vd = *(const ushort4*)(h16 + (size_t)sd4*256 + lane*4);
    float la = als[sa*4+hh], lb = als[sb*4+hh], lc = als[sc*4+hh], ld = als[sd4*4+hh];
    float ea = __expf(lrelu(la + ad));
    float eb = __expf(lrelu(lb + ad));
    float ec = __expf(lrelu(lc + ad));
    float ed = __expf(lrelu(ld + ad));
    den += (ea+eb)+(ec+ed);
    float qa0=__shfl(ea,base), qa1=__shfl(ea,base+1), qa2=__shfl(ea,base+2), qa3=__shfl(ea,base+3);
    float qb0=__shfl(eb,base), qb1=__shfl(eb,base+1), qb2=__shfl(eb,base+2), qb3=__shfl(eb,base+3);
    float qc0=__shfl(ec,base), qc1=__shfl(ec,base+1), qc2=__shfl(ec,base+2), qc3=__shfl(ec,base+3);
    float qd0=__shfl(ed,base), qd1=__shfl(ed,base+1), qd2=__shfl(ed,base+2), qd3=__shfl(ed,base+3);
    num0 += qa0*bf2f(va.x) + qb0*bf2f(vb.x) + qc0*bf2f(vc.x) + qd0*bf2f(vd.x);
    num1 += qa1*bf2f(va.y) + qb1*bf2f(vb.y) + qc1*bf2f(vc.y) + qd1*bf2f(vd.y);
    num2 += qa2*bf2f(va.z) + qb2*bf2f(vb.z) + qc2*bf2f(vc.z) + qd2*bf2f(vd.z);
    num3 += qa3*bf2f(va.w) + qb3*bf2f(vb.w) + qc3*bf2f(vc.w) + qd3*bf2f(vd.w);
  }
  for (; p < p1; ++p) {
    int s = es[p];
    ushort4 va = *(const ushort4*)(h16 + (size_t)s*256 + lane*4);
    float e = __expf(lrelu(als[s*4 + hh] + ad));
    den += e;
    float q0 = __shfl(e, base), q1 = __shfl(e, base+1), q2 = __shfl(e, base+2), q3 = __shfl(e, base+3);
    num0 += q0*bf2f(va.x); num1 += q1*bf2f(va.y); num2 += q2*bf2f(va.z); num3 += q3*bf2f(va.w);
  }
  float rd = 1.f/(den + 1e-16f);
  float r0 = __shfl(rd, base), r1 = __shfl(rd, base+1), r2 = __shfl(rd, base+2), r3 = __shfl(rd, base+3);
  return num0*r0 + num1*r1 + num2*r2 + num3*r3;
}

// ---------------- pre: encoder (compile-time unrolled) + CSR histogram + weight prep ----------------
__global__ __launch_bounds__(256) void k_pre(const float* xA, const float* xT,
    const float* aeW, const float* aeB, const float* teW, const float* teB,
    const int* d0_, const int* d1_, const int* d2_, const int* d3_,
    const float* convW, const float* convAsrc, const float* convAdst, float* ws) {
  int bid = blockIdx.x;
  int t = threadIdx.x;
  __shared__ float xs[4][48];
  if (bid < 2000) {
    // agent encoder, F=32 (compile-time unroll)
    int wv = t >> 6, lane = t & 63;
    int n = bid*4 + wv;
    if (lane < 32) xs[wv][lane] = xA[(size_t)n*32 + lane];
    __syncthreads();
    float acc = aeB[lane];
    #pragma unroll
    for (int k = 0; k < 32; ++k) acc += xs[wv][k] * aeW[k*64 + lane];
    ws[XA_OFF + (size_t)n*64 + lane] = fmaxf(acc, 0.f);
  } else if (bid < 9500) {
    // track encoder, F=48 (compile-time unroll)
    int wv = t >> 6, lane = t & 63;
    int n = (bid - 2000)*4 + wv;
    if (lane < 48) xs[wv][lane] = xT[(size_t)n*48 + lane];
    __syncthreads();
    float acc = teB[lane];
    #pragma unroll
    for (int k = 0; k < 48; ++k) acc += xs[wv][k] * teW[k*64 + lane];
    ws[XT_OFF + (size_t)n*64 + lane] = fmaxf(acc, 0.f);
  } else if (bid < 11844) {
    int idx = bid - 9500;
    int r = idx / 586, eb = idx % 586;
    const int* dp = r==0? d0_ : r==1? d1_ : r==2? d2_ : d3_;
    int e = eb*256 + t;
    if (e < NE) atomicAdd(&((int*)ws)[ROWP_I + r*RELSTRIDE + dp[e]], 1);
  } else {
    int lr = bid - 11844;            // layer*4 + r
    int layer = lr >> 2, r = lr & 3;
    const float* W = convW + (size_t)lr*64*256;
    float* W2 = ws + W2B + (size_t)lr*64*256;
    int c = t >> 2, h = t & 3;
    #pragma unroll 4
    for (int k = 0; k < 64; ++k) W2[k*256 + t] = W[k*256 + h*64 + c];
    int k = t >> 2;
    const float* ad = convAdst + (size_t)lr*256;
    const float* as = convAsrc + (size_t)lr*256;
    float s0 = 0.f, s1 = 0.f;
    #pragma unroll 4
    for (int cc = 0; cc < 64; ++cc) {
      float w = W[k*256 + h*64 + cc];
      s0 += w * ad[h*64 + cc];
      s1 += w * as[h*64 + cc];
    }
    ws[WVB + (size_t)(layer*8 + 0*4 + r)*256 + t] = s0;   // side 0: ald
    ws[WVB + (size_t)(layer*8 + 1*4 + r)*256 + t] = s1;   // side 1: als
  }
}

// ---------------- CSR build: exclusive scan per relation ----------------
__global__ __launch_bounds__(256) void k_scan(int* wsi) {
  int r = blockIdx.x;
  int n = ((r & 1) ? NAg : NTr) + 1;
  int* rp = wsi + ROWP_I + r*RELSTRIDE;
  __shared__ int part[256];
  int t = threadIdx.x;
  int chunk = (n + 255) / 256;
  int lo = t*chunk, hi = min(lo + chunk, n);
  int s = 0;
  for (int i = lo; i < hi; ++i) s += rp[i];
  part[t] = s;
  __syncthreads();
  if (t == 0) {
    int run = 0;
    for (int i = 0; i < 256; ++i) { int tm = part[i]; part[i] = run; run += tm; }
  }
  __syncthreads();
  int run = part[t];
  for (int i = lo; i < hi; ++i) { int tm = rp[i]; rp[i] = run; run += tm; }
}

// ---------------- CSR build: fill sorted src lists ----------------
__global__ __launch_bounds__(256) void k_fill(const int* s0,const int* d0_,const int* s1,const int* d1_,
    const int* s2,const int* d2_,const int* s3,const int* d3_, int* wsi) {
  int r = blockIdx.y;
  const int* sp = r==0? s0 : r==1? s1 : r==2? s2 : s3;
  const int* dp = r==0? d0_ : r==1? d1_ : r==2? d2_ : d3_;
  int e = blockIdx.x*256 + threadIdx.x;
  if (e >= NE) return;
  int d = dp[e];
  int pos = wsi[ROWP_I + r*RELSTRIDE + d] + atomicAdd(&wsi[CURS_I + r*RELSTRIDE + d], 1);
  wsi[ESRC_I + r*NE + pos] = sp[e];
}

// ---------------- alpha logits: wave per node, coalesced; zeroes BNSTB ----------------
__global__ __launch_bounds__(256) void k_alx(float* ws, int layer) {
  int bid = blockIdx.x;
  int t = threadIdx.x;
  if (bid < 64) ws[BNSTB + bid*256 + t] = 0.f;
  int y, b0;
  if (bid < 7500)       { y = 0; b0 = bid; }
  else if (bid < 9500)  { y = 1; b0 = bid - 7500; }
  else if (bid < 17000) { y = 2; b0 = bid - 9500; }
  else if (bid < 19000) { y = 3; b0 = bid - 17000; }
  else if (bid < 21000) { y = 4; b0 = bid - 19000; }
  else if (bid < 28500) { y = 5; b0 = bid - 21000; }
  else if (bid < 30500) { y = 6; b0 = bid - 28500; }
  else                  { y = 7; b0 = bid - 30500; }
  int side = y >> 2, r = y & 3;
  int wv = t >> 6, lane = t & 63;
  int n = b0*4 + wv;
  const float* xv = ws + (side ? ((r & 1) ? XT_OFF : XA_OFF) : ((r & 1) ? XA_OFF : XT_OFF));
  float4 wv4 = *(const float4*)(ws + WVB + (size_t)(layer*8 + y)*256 + lane*4);
  float xk = xv[(size_t)n*64 + lane];
  float p0 = wred64(xk * wv4.x);
  float p1 = wred64(xk * wv4.y);
  float p2 = wred64(xk * wv4.z);
  float p3 = wred64(xk * wv4.w);
  if (lane == 0) {
    float4 o; o.x = p0; o.y = p1; o.z = p2; o.w = p3;
    *(float4*)(ws + (side ? selALS(r) : selALD(r)) + (size_t)n*4) = o;
  }
}

// ---------------- h = x_src @ W2 (bf16 interleaved store), flattened grid ----------------
__global__ __launch_bounds__(256) void k_hgemm(float* ws, int layer) {
  int tile = blockIdx.x;          // 4750 tiles: r0:500, r1:1875, r2:500, r3:1875
  int r, row0;
  if (tile < 500)        { r = 0; row0 = tile*16; }
  else if (tile < 2375)  { r = 1; row0 = (tile-500)*16; }
  else if (tile < 2875)  { r = 2; row0 = (tile-2375)*16; }
  else                   { r = 3; row0 = (tile-2875)*16; }
  const float* W2 = ws + W2B + (size_t)(layer*4 + r)*64*256;
  const float* xg = ws + ((r & 1) ? XT_OFF : XA_OFF);
  ushortT* h16 = (ushortT*)(ws + selH(r));
  __shared__ float xs[16][64];
  int t = threadIdx.x;
  #pragma unroll
  for (int i = 0; i < 4; ++i) {
    int lin = i*256 + t;
    xs[lin>>6][lin&63] = xg[((size_t)row0 + (lin>>6))*64 + (lin&63)];
  }
  __syncthreads();
  int c0 = t & 63;
  int tr = t >> 6;
  float acc[4][4];
  #pragma unroll
  for (int i=0;i<4;i++){ acc[i][0]=0;acc[i][1]=0;acc[i][2]=0;acc[i][3]=0; }
  const float* Wc = W2 + c0*4;
  for (int k4 = 0; k4 < 16; ++k4) {
    float4 xv[4];
    #pragma unroll
    for (int i = 0; i < 4; ++i) xv[i] = *(const float4*)&xs[tr*4+i][k4*4];
    #pragma unroll
    for (int kk = 0; kk < 4; ++kk) {
      int k = k4*4 + kk;
      float4 w4 = *(const float4*)(Wc + k*256);
      #pragma unroll
      for (int i = 0; i < 4; ++i) {
        float x = (kk==0)?xv[i].x:(kk==1)?xv[i].y:(kk==2)?xv[i].z:xv[i].w;
        acc[i][0] += x*w4.x; acc[i][1] += x*w4.y; acc[i][2] += x*w4.z; acc[i][3] += x*w4.w;
      }
    }
  }
  #pragma unroll
  for (int i = 0; i < 4; ++i) {
    int row = row0 + tr*4 + i;
    ushort4 pk;
    pk.x = f2bf(acc[i][0]); pk.y = f2bf(acc[i][1]);
    pk.z = f2bf(acc[i][2]); pk.w = f2bf(acc[i][3]);
    *(ushort4*)(h16 + (size_t)row*256 + c0*4) = pk;
  }
}

// ---------------- fused CSR aggregation, flattened grid, agents-first ----------------
__global__ __launch_bounds__(256) void k_agg(const float* convBias, float* ws, int layer) {
  int t = threadIdx.x, wv = t >> 6, lane = t & 63, hh = lane & 3, base = lane & ~3;
  const int* wsi = (const int*)ws;
  int bid = blockIdx.x;
  __shared__ float part[4][64];
  __shared__ float sh1[4][64];
  __shared__ float sh2[4][64];
  if (bid < 4000) {
    int node = bid*2 + (wv >> 1);
    int rr = wv & 1;
    int r = rr ? 3 : 1;
    const int* rp = wsi + ROWP_I + r*RELSTRIDE;
    const int* es = wsi + ESRC_I + r*NE;
    const float* als = ws + selALS(r);
    const ushortT* h16 = (const ushortT*)(ws + selH(r));
    float ad = (ws + selALD(r))[node*4 + hh];
    part[wv][lane] = agg_rel(es, rp[node], rp[node+1], als, h16, ad, lane, hh, base);
    __syncthreads();
    if (rr == 0) {
      float o = part[wv][lane] + part[wv+1][lane];
      float bavg = 0.5f*(convBias[(layer*4 + 1)*64 + lane] + convBias[(layer*4 + 3)*64 + lane]);
      float z = fmaxf(o*0.125f + bavg, 0.f);
      ws[OAACC + (size_t)node*64 + lane] = z;
      sh1[wv][lane] = z; sh2[wv][lane] = z*z;
    } else {
      sh1[wv][lane] = 0.f; sh2[wv][lane] = 0.f;
    }
    __syncthreads();
    if (t < 64) {
      float s1 = sh1[0][t] + sh1[1][t] + sh1[2][t] + sh1[3][t];
      float s2 = sh2[0][t] + sh2[1][t] + sh2[2][t] + sh2[3][t];
      int bucket = bid & 63;
      atomicAdd(&ws[BNSTB + bucket*256 + t], s1);            // bt=0 agent
      atomicAdd(&ws[BNSTB + bucket*256 + 64 + t], s2);
    }
  } else {
    int node = (bid - 4000)*4 + wv;
    float outv = 0.f;
    #pragma unroll
    for (int rr = 0; rr < 2; ++rr) {
      int r = rr ? 2 : 0;
      const int* rp = wsi + ROWP_I + r*RELSTRIDE;
      const int* es = wsi + ESRC_I + r*NE;
      const float* als = ws + selALS(r);
      const ushortT* h16 = (const ushortT*)(ws + selH(r));
      float ad = (ws + selALD(r))[node*4 + hh];
      outv += agg_rel(es, rp[node], rp[node+1], als, h16, ad, lane, hh, base);
    }
    float bavg = 0.5f*(convBias[(layer*4 + 0)*64 + lane] + convBias[(layer*4 + 2)*64 + lane]);
    float z = fmaxf(outv*0.125f + bavg, 0.f);
    ws[OTACC + (size_t)node*64 + lane] = z;
    sh1[wv][lane] = z; sh2[wv][lane] = z*z;
    __syncthreads();
    if (t < 64) {
      float s1 = sh1[0][t] + sh1[1][t] + sh1[2][t] + sh1[3][t];
      float s2 = sh2[0][t] + sh2[1][t] + sh2[2][t] + sh2[3][t];
      int bucket = bid & 63;
      atomicAdd(&ws[BNSTB + bucket*256 + 128 + t], s1);      // bt=1 track
      atomicAdd(&ws[BNSTB + bucket*256 + 192 + t], s2);
    }
  }
}

// ---------------- reduce 64 BN-stat buckets -> BNST; optionally zero critic buckets ----------------
__global__ __launch_bounds__(256) void k_bnred2(float* ws, int zero_cstb) {
  int t = threadIdx.x;
  float s = 0.f;
  #pragma unroll
  for (int b = 0; b < 64; ++b) s += ws[BNSTB + b*256 + t];
  ws[BNST + t] = s;
  if (zero_cstb) {
    for (int i = t; i < 24576; i += 256) ws[CSTB + i] = 0.f;
  }
}

// ---------------- batchnorm + residual, flattened grid (layers 0,1) ----------------
__global__ __launch_bounds__(256) void k_bnnorm(const float* bnG, const float* bnB, float* ws, int layer) {
  int bid = blockIdx.x;
  int type, i;
  if (bid < 2000) { type = 0; i = bid*256 + threadIdx.x; }
  else            { type = 1; i = (bid - 2000)*256 + threadIdx.x; }
  float* acc = ws + (type ? OTACC : OAACC);
  float* x = ws + (type ? XT_OFF : XA_OFF);
  int c = i & 63;
  float Nf = type ? 30000.f : 8000.f;
  float s1 = ws[BNST + type*128 + c], s2 = ws[BNST + type*128 + 64 + c];
  float mu = s1/Nf, var = s2/Nf - mu*mu;
  float g = bnG[(layer*2 + type)*64 + c], b = bnB[(layer*2 + type)*64 + c];
  float y = g*(acc[i]-mu)*rsqrtf(var + 1e-5f) + b;
  if (layer > 0) y += x[i];
  x[i] = y;
}

// ---------------- tail: BN(layer2)+residual -> x, fused bucketed critic stats ----------------
__global__ __launch_bounds__(256) void k_bncrit(const float* bnG, const float* bnB, float* ws) {
  int bid = blockIdx.x;
  int t = threadIdx.x;
  int type, i0;
  if (bid < 2000) { type = 0; i0 = bid*256; }
  else            { type = 1; i0 = (bid-2000)*256; }
  float* acc = ws + (type ? OTACC : OAACC);
  float* x = ws + (type ? XT_OFF : XA_OFF);
  int i = i0 + t;
  int c = i & 63;
  float Nf = type ? 30000.f : 8000.f;
  float s1 = ws[BNST + type*128 + c], s2 = ws[BNST + type*128 + 64 + c];
  float mu = s1/Nf, var = s2/Nf - mu*mu;
  float g = bnG[(2*2+type)*64 + c], b = bnB[(2*2+type)*64 + c];
  float y = g*(acc[i]-mu)*rsqrtf(var+1e-5f) + b + x[i];
  x[i] = y;
  __shared__ float sd[3][256];
  sd[0][t] = y; sd[1][t] = y*y; sd[2][t] = y;
  __syncthreads();
  if (t < 64) {
    float a1 = sd[0][t]+sd[0][t+64]+sd[0][t+128]+sd[0][t+192];
    float a2 = sd[1][t]+sd[1][t+64]+sd[1][t+128]+sd[1][t+192];
    float mx = fmaxf(fmaxf(sd[2][t],sd[2][t+64]), fmaxf(sd[2][t+128],sd[2][t+192]));
    int bucket = bid & 63;
    atomicAdd(&ws[CSTB + bucket*384 + type*192 + t], a1);
    atomicAdd(&ws[CSTB + bucket*384 + type*192 + 64 + t], a2);
    atomicMax((unsigned*)&ws[CSTB + bucket*384 + type*192 + 128 + t], fmap(mx));
  }
}

// ---------------- actor heads: wave per node, both heads in parallel, flattened ----------------
__global__ __launch_bounds__(256) void k_actor(const float* aW1, const float* ab1, const float* ag,
    const float* abe, const float* aW2, const float* ab2, const float* ws, float* out) {
  int bid = blockIdx.x;
  int type, nb;
  if (bid < 2000) { type = 0; nb = bid; } else { type = 1; nb = bid - 2000; }
  int t = threadIdx.x, wv = t >> 6, lane = t & 63;
  int p = lane >> 5, j = lane & 31;
  int n = nb*4 + wv;
  const float* xg = ws + (type ? XT_OFF : XA_OFF);
  __shared__ float xsh[4][64];
  xsh[wv][lane] = xg[(size_t)n*64 + lane];
  __syncthreads();
  int i = (type ? 2 : 0) + p;
  const float* W = aW1 + i*2048 + j;
  float a0 = 0.f, a1 = 0.f, a2 = 0.f, a3 = 0.f;
  #pragma unroll
  for (int k = 0; k < 64; k += 4) {
    a0 += xsh[wv][k]   * W[k*32];
    a1 += xsh[wv][k+1] * W[(k+1)*32];
    a2 += xsh[wv][k+2] * W[(k+2)*32];
    a3 += xsh[wv][k+3] * W[(k+3)*32];
  }
  float tv = ((a0+a1)+(a2+a3)) + ab1[i*32 + j];
  float mu = wred32(tv) * (1.f/32.f);
  float dz = tv - mu;
  float var = wred32(dz*dz) * (1.f/32.f);
  float hn = fmaxf(ag[i*32+j]*dz*rsqrtf(var + 1e-5f) + abe[i*32+j], 0.f);
  float s = wred32(hn * aW2[i*32 + j]) + ab2[i];
  float val = softplusf(s) + 1.f;
  float vA = __shfl(val, 0);
  float vB = __shfl(val, 32);
  if (lane == 0) {
    int offA = type ? 24000 : 0, offB = type ? 54000 : 8000, offC = type ? 84000 : 16000;
    out[offA + n] = vA;
    out[offB + n] = vB;
    out[offC + n] = vA / (vA + vB);
  }
}

__device__ __forceinline__ float blocksum128(float v, float* red) {
  int t = threadIdx.x;
  red[t] = v; __syncthreads();
  #pragma unroll
  for (int s = 64; s > 0; s >>= 1) { if (t < s) red[t] += red[t+s]; __syncthreads(); }
  float r = red[0]; __syncthreads();
  return r;
}

// ---------------- critic MLP (reduces CSTB buckets in prologue) ----------------
__global__ __launch_bounds__(128) void k_critic(const float* cW1,const float* cb1,const float* cg1,const float* cbe1,
    const float* cW2,const float* cb2,const float* cg2,const float* cbe2,
    const float* cW3,const float* cb3,const float* cW4,const float* cb4,
    const float* ws, float* out) {
  __shared__ float g[384];
  __shared__ float h1[128];
  __shared__ float h2s[64];
  __shared__ float red[128];
  int t = threadIdx.x;
  if (t < 64) {
    #pragma unroll
    for (int type = 0; type < 2; ++type) {
      float s1 = 0.f, s2 = 0.f;
      unsigned mu_ = 0u;
      for (int b2 = 0; b2 < 64; ++b2) {
        s1 += ws[CSTB + b2*384 + type*192 + t];
        s2 += ws[CSTB + b2*384 + type*192 + 64 + t];
        unsigned u = __float_as_uint(ws[CSTB + b2*384 + type*192 + 128 + t]);
        mu_ = max(mu_, u);
      }
      float Nf = type ? 30000.f : 8000.f;
      float mean = s1 / Nf;
      float sd = sqrtf(fmaxf((s2 - Nf*mean*mean) / (Nf - 1.f), 0.f));
      g[type*192 + t] = mean;
      g[type*192 + 64 + t] = funmap(mu_);
      g[type*192 + 128 + t] = sd;
    }
  }
  __syncthreads();
  float v = cb1[t];
  for (int k = 0; k < 384; ++k) v += g[k] * cW1[k*128 + t];
  float mu = blocksum128(v, red) * (1.f/128.f);
  float d = v - mu;
  float var = blocksum128(d*d, red) * (1.f/128.f);
  h1[t] = fmaxf(cg1[t]*d*rsqrtf(var + 1e-5f) + cbe1[t], 0.f);
  __syncthreads();
  float v2 = 0.f;
  if (t < 64) { v2 = cb2[t]; for (int k = 0; k < 128; ++k) v2 += h1[k] * cW2[k*64 + t]; }
  float mu2 = blocksum128(t < 64 ? v2 : 0.f, red) * (1.f/64.f);
  float d2 = v2 - mu2;
  float var2 = blocksum128(t < 64 ? d2*d2 : 0.f, red) * (1.f/64.f);
  if (t < 64) h2s[t] = fmaxf(cg2[t]*d2*rsqrtf(var2 + 1e-5f) + cbe2[t], 0.f);
  __syncthreads();
  float v3 = 0.f;
  if (t < 32) {
    v3 = cb3[t];
    for (int k = 0; k < 64; ++k) v3 += h2s[k] * cW3[k*32 + t];
    v3 = fmaxf(v3, 0.f);
  }
  float s4 = blocksum128(t < 32 ? v3 * cW4[t] : 0.f, red);
  if (t == 0) out[114000] = s4 + cb4[0];
}

extern "C" void kernel_launch(void* const* d_in, const int* in_sizes, int n_in,
                              void* d_out, int out_size, void* d_ws, size_t ws_size,
                              hipStream_t stream) {
  const float* x_agent = (const float*)d_in[0];
  const float* x_track = (const float*)d_in[1];
  const int* s0 = (const int*)d_in[2]; const int* d0_ = (const int*)d_in[3];
  const int* s1 = (const int*)d_in[4]; const int* d1_ = (const int*)d_in[5];
  const int* s2 = (const int*)d_in[6]; const int* d2_ = (const int*)d_in[7];
  const int* s3 = (const int*)d_in[8]; const int* d3_ = (const int*)d_in[9];
  const float* aeW = (const float*)d_in[10]; const float* aeB = (const float*)d_in[11];
  const float* teW = (const float*)d_in[12]; const float* teB = (const float*)d_in[13];
  const float* convW    = (const float*)d_in[14];
  const float* convAsrc = (const float*)d_in[15];
  const float* convAdst = (const float*)d_in[16];
  const float* convBias = (const float*)d_in[17];
  const float* bnG = (const float*)d_in[18]; const float* bnB = (const float*)d_in[19];
  const float* aW1 = (const float*)d_in[20]; const float* ab1 = (const float*)d_in[21];
  const float* ag  = (const float*)d_in[22]; const float* abe = (const float*)d_in[23];
  const float* aW2 = (const float*)d_in[24]; const float* ab2 = (const float*)d_in[25];
  const float* cW1 = (const float*)d_in[26]; const float* cb1 = (const float*)d_in[27];
  const float* cg1 = (const float*)d_in[28]; const float* cbe1 = (const float*)d_in[29];
  const float* cW2 = (const float*)d_in[30]; const float* cb2 = (const float*)d_in[31];
  const float* cg2 = (const float*)d_in[32]; const float* cbe2 = (const float*)d_in[33];
  const float* cW3 = (const float*)d_in[34]; const float* cb3 = (const float*)d_in[35];
  const float* cW4 = (const float*)d_in[36]; const float* cb4 = (const float*)d_in[37];
  float* ws = (float*)d_ws;
  int* wsi = (int*)d_ws;
  float* out = (float*)d_out;

  hipMemsetAsync(wsi + ROWP_I, 0, (size_t)240128 * sizeof(int), stream);

  k_pre<<<dim3(11856), 256, 0, stream>>>(x_agent, x_track, aeW, aeB, teW, teB,
                                         d0_, d1_, d2_, d3_, convW, convAsrc, convAdst, ws);
  k_scan<<<dim3(4), 256, 0, stream>>>(wsi);
  k_fill<<<dim3(586, 4), 256, 0, stream>>>(s0,d0_,s1,d1_,s2,d2_,s3,d3_, wsi);

  for (int l = 0; l < 3; ++l) {
    k_alx<<<dim3(38000), 256, 0, stream>>>(ws, l);
    k_hgemm<<<dim3(4750), 256, 0, stream>>>(ws, l);
    k_agg<<<dim3(11500), 256, 0, stream>>>(convBias, ws, l);
    k_bnred2<<<dim3(1), 256, 0, stream>>>(ws, l == 2 ? 1 : 0);
    if (l < 2) k_bnnorm<<<dim3(9500), 256, 0, stream>>>(bnG, bnB, ws, l);
  }

  k_bncrit<<<dim3(9500), 256, 0, stream>>>(bnG, bnB, ws);
  k_actor<<<dim3(9500), 256, 0, stream>>>(aW1, ab1, ag, abe, aW2, ab2, ws, out);
  k_critic<<<1, 128, 0, stream>>>(cW1,cb1,cg1,cbe1,cW2,cb2,cg2,cbe2,cW3,cb3,cW4,cb4, ws, out);
}

// Round 17
// 637.534 us; speedup vs baseline: 1.5304x; 1.0236x over previous
//
#include <hip/hip_runtime.h>
#include <math.h>

#define NAg 8000
#define NTr 30000
#define NE  150000

// ---- workspace layout (float offsets) ----
#define XA_OFF 0          // 8000*64
#define XT_OFF 512000     // 30000*64
#define H0_OFF 2432000    // bf16 interleaved [node][c*4+h], 256 ushorts/node
#define H1_OFF 4480000
#define H2_OFF 12160000
#define H3_OFF 14208000   // bf16 ends at float 18048000
#define BNSTB 8320000     // 64 buckets x [2][128] = 16384 floats
#define WVB   8336384     // [layer][side*4+r][256] = 6144 floats
#define W2B   8342528     // [layer][r][64][256] fp32 interleaved = 196608 floats
#define CSTB  18100000    // 64 buckets x [type][192] = 24576 floats
#define ALS0 21888000
#define ALS1 21920000
#define ALS2 22040000
#define ALS3 22072000
#define ALD0 22192000
#define ALD1 22312000
#define ALD2 22344000
#define ALD3 22464000
#define ESRC_I 22496000   // int offsets into (int*)ws; 4 x 150000
#define OAACC 23104000    // 8000*64
#define OTACC 23616000    // 30000*64
#define BNST 25536000     // [type: 0 agent,1 track][2][64]
#define ROWP_I 25536640   // 4 x 30016 ints
#define CURS_I 25656704   // 4 x 30016 ints
#define RELSTRIDE 30016

typedef unsigned short ushortT;

__device__ __forceinline__ float lrelu(float x){ return x >= 0.f ? x : 0.2f*x; }
__device__ __forceinline__ unsigned fmap(float f){ unsigned u=__float_as_uint(f); return (u&0x80000000u)? ~u : (u|0x80000000u); }
__device__ __forceinline__ float funmap(unsigned u){ return (u&0x80000000u)? __uint_as_float(u&0x7FFFFFFFu) : __uint_as_float(~u); }
__device__ __forceinline__ float softplusf(float x){ return fmaxf(x,0.f) + log1pf(expf(-fabsf(x))); }
__device__ __forceinline__ ushortT f2bf(float f){
  unsigned u = __float_as_uint(f);
  unsigned r = u + 0x7FFFu + ((u>>16)&1u);   // RNE
  return (ushortT)(r>>16);
}
__device__ __forceinline__ float bf2f(ushortT s){ return __uint_as_float(((unsigned)s)<<16); }
__device__ __forceinline__ float wred64(float v){
  #pragma unroll
  for (int o=32;o;o>>=1) v += __shfl_xor(v,o);
  return v;
}
__device__ __forceinline__ float wred32(float v){
  #pragma unroll
  for (int o=16;o;o>>=1) v += __shfl_xor(v,o,32);
  return v;
}
__device__ __forceinline__ int selH(int r){ return r==0?H0_OFF: r==1?H1_OFF: r==2?H2_OFF:H3_OFF; }
__device__ __forceinline__ int selALS(int r){ return r==0?ALS0: r==1?ALS1: r==2?ALS2:ALS3; }
__device__ __forceinline__ int selALD(int r){ return r==0?ALD0: r==1?ALD1: r==2?ALD2:ALD3; }

// per-relation softmax-weighted aggregation for one node's edge list (shuffle version)
__device__ __forceinline__ float agg_rel(const int* es, int p, int p1, const float* als,
                                         const ushortT* h16, float ad, int lane, int hh, int base) {
  float num0=0.f, num1=0.f, num2=0.f, num3=0.f, den=0.f;
  for (; p + 4 <= p1; p += 4) {
    int sa = es[p], sb = es[p+1], sc = es[p+2], sd4 = es[p+3];
    ushort4 va = *(const ushort4*)(h16 + (size_t)sa*256 + lane*4);
    ushort4 vb = *(const ushort4*)(h16 + (size_t)sb*256 + lane*4);
    ushort4 vc = *(const ushort4*)(h16 + (size_t)sc*256 + lane*4);
    ushort4 vd = *(const ushort4*)(h16 + (size_t)sd4*256 + lane*4);
    float la = als[sa*4+hh], lb = als[sb*4+hh], lc = als[sc*4+hh], ld = als[sd4*4+hh];
    float ea = __expf(lrelu(la + ad));
    float eb = __expf(lrelu(lb + ad));
    float ec = __expf(lrelu(lc + ad));
    float ed = __expf(lrelu(ld + ad));
    den += (ea+eb)+(ec+ed);
    float qa0=__shfl(ea,base), qa1=__shfl(ea,base+1), qa2=__shfl(ea,base+2), qa3=__shfl(ea,base+3);
    float qb0=__shfl(eb,base), qb1=__shfl(eb,base+1), qb2=__shfl(eb,base+2), qb3=__shfl(eb,base+3);
    float qc0=__shfl(ec,base), qc1=__shfl(ec,base+1), qc2=__shfl(ec,base+2), qc3=__shfl(ec,base+3);
    float qd0=__shfl(ed,base), qd1=__shfl(ed,base+1), qd2=__shfl(ed,base+2), qd3=__shfl(ed,base+3);
    num0 += qa0*bf2f(va.x) + qb0*bf2f(vb.x) + qc0*bf2f(vc.x) + qd0*bf2f(vd.x);
    num1 += qa1*bf2f(va.y) + qb1*bf2f(vb.y) + qc1*bf2f(vc.y) + qd1*bf2f(vd.y);
    num2 += qa2*bf2f(va.z) + qb2*bf2f(vb.z) + qc2*bf2f(vc.z) + qd2*bf2f(vd.z);
    num3 += qa3*bf2f(va.w) + qb3*bf2f(vb.w) + qc3*bf2f(vc.w) + qd3*bf2f(vd.w);
  }
  for (; p < p1; ++p) {
    int s = es[p];
    ushort4 va = *(const ushort4*)(h16 + (size_t)s*256 + lane*4);
    float e = __expf(lrelu(als[s*4 + hh] + ad));
    den += e;
    float q0 = __shfl(e, base), q1 = __shfl(e, base+1), q2 = __shfl(e, base+2), q3 = __shfl(e, base+3);
    num0 += q0*bf2f(va.x); num1 += q1*bf2f(va.y); num2 += q2*bf2f(va.z); num3 += q3*bf2f(va.w);
  }
  float rd = 1.f/(den + 1e-16f);
  float r0 = __shfl(rd, base), r1 = __shfl(rd, base+1), r2 = __shfl(rd, base+2), r3 = __shfl(rd, base+3);
  return num0*r0 + num1*r1 + num2*r2 + num3*r3;
}

// ---------------- pre: encoder + CSR histogram + weight prep (k-sliced, 96 blocks) ----------------
__global__ __launch_bounds__(256) void k_pre(const float* xA, const float* xT,
    const float* aeW, const float* aeB, const float* teW, const float* teB,
    const int* d0_, const int* d1_, const int* d2_, const int* d3_,
    const float* convW, const float* convAsrc, const float* convAdst, float* ws) {
  int bid = blockIdx.x;
  int t = threadIdx.x;
  __shared__ float xs[4][48];
  if (bid < 2000) {
    // agent encoder, F=32
    int wv = t >> 6, lane = t & 63;
    int n = bid*4 + wv;
    if (lane < 32) xs[wv][lane] = xA[(size_t)n*32 + lane];
    __syncthreads();
    float acc = aeB[lane];
    #pragma unroll
    for (int k = 0; k < 32; ++k) acc += xs[wv][k] * aeW[k*64 + lane];
    ws[XA_OFF + (size_t)n*64 + lane] = fmaxf(acc, 0.f);
  } else if (bid < 9500) {
    // track encoder, F=48
    int wv = t >> 6, lane = t & 63;
    int n = (bid - 2000)*4 + wv;
    if (lane < 48) xs[wv][lane] = xT[(size_t)n*48 + lane];
    __syncthreads();
    float acc = teB[lane];
    #pragma unroll
    for (int k = 0; k < 48; ++k) acc += xs[wv][k] * teW[k*64 + lane];
    ws[XT_OFF + (size_t)n*64 + lane] = fmaxf(acc, 0.f);
  } else if (bid < 11844) {
    int idx = bid - 9500;
    int r = idx / 586, eb = idx % 586;
    const int* dp = r==0? d0_ : r==1? d1_ : r==2? d2_ : d3_;
    int e = eb*256 + t;
    if (e < NE) atomicAdd(&((int*)ws)[ROWP_I + r*RELSTRIDE + dp[e]], 1);
  } else {
    // weight prep, k-sliced: 96 blocks = 12 (layer,rel) x 8 slices of 8 k-values
    int idx = bid - 11844;
    int lr = idx >> 3, slice = idx & 7;
    int k0 = slice * 8;
    int layer = lr >> 2, r = lr & 3;
    const float* W = convW + (size_t)lr*64*256;
    float* W2 = ws + W2B + (size_t)lr*64*256;
    int c = t >> 2, h = t & 3;
    #pragma unroll
    for (int kk = 0; kk < 8; ++kk) {
      int k = k0 + kk;
      W2[k*256 + t] = W[k*256 + h*64 + c];
    }
    // Wv: 32 threads cover this slice's (k,h) outputs, full-unrolled cc reduction
    if (t < 32) {
      int k = k0 + (t >> 2), hh = t & 3;
      const float* ad = convAdst + (size_t)lr*256;
      const float* as = convAsrc + (size_t)lr*256;
      float s0 = 0.f, s1 = 0.f;
      #pragma unroll
      for (int cc = 0; cc < 64; ++cc) {
        float w = W[k*256 + hh*64 + cc];
        s0 += w * ad[hh*64 + cc];
        s1 += w * as[hh*64 + cc];
      }
      ws[WVB + (size_t)(layer*8 + 0*4 + r)*256 + k*4 + hh] = s0;   // side 0: ald
      ws[WVB + (size_t)(layer*8 + 1*4 + r)*256 + k*4 + hh] = s1;   // side 1: als
    }
  }
}

// ---------------- CSR build: exclusive scan per relation ----------------
__global__ __launch_bounds__(256) void k_scan(int* wsi) {
  int r = blockIdx.x;
  int n = ((r & 1) ? NAg : NTr) + 1;
  int* rp = wsi + ROWP_I + r*RELSTRIDE;
  __shared__ int part[256];
  int t = threadIdx.x;
  int chunk = (n + 255) / 256;
  int lo = t*chunk, hi = min(lo + chunk, n);
  int s = 0;
  for (int i = lo; i < hi; ++i) s += rp[i];
  part[t] = s;
  __syncthreads();
  if (t == 0) {
    int run = 0;
    for (int i = 0; i < 256; ++i) { int tm = part[i]; part[i] = run; run += tm; }
  }
  __syncthreads();
  int run = part[t];
  for (int i = lo; i < hi; ++i) { int tm = rp[i]; rp[i] = run; run += tm; }
}

// ---------------- CSR build: fill sorted src lists ----------------
__global__ __launch_bounds__(256) void k_fill(const int* s0,const int* d0_,const int* s1,const int* d1_,
    const int* s2,const int* d2_,const int* s3,const int* d3_, int* wsi) {
  int r = blockIdx.y;
  const int* sp = r==0? s0 : r==1? s1 : r==2? s2 : s3;
  const int* dp = r==0? d0_ : r==1? d1_ : r==2? d2_ : d3_;
  int e = blockIdx.x*256 + threadIdx.x;
  if (e >= NE) return;
  int d = dp[e];
  int pos = wsi[ROWP_I + r*RELSTRIDE + d] + atomicAdd(&wsi[CURS_I + r*RELSTRIDE + d], 1);
  wsi[ESRC_I + r*NE + pos] = sp[e];
}

// ---------------- alpha logits: wave per node, coalesced; zeroes BNSTB ----------------
__global__ __launch_bounds__(256) void k_alx(float* ws, int layer) {
  int bid = blockIdx.x;
  int t = threadIdx.x;
  if (bid < 64) ws[BNSTB + bid*256 + t] = 0.f;
  int y, b0;
  if (bid < 7500)       { y = 0; b0 = bid; }
  else if (bid < 9500)  { y = 1; b0 = bid - 7500; }
  else if (bid < 17000) { y = 2; b0 = bid - 9500; }
  else if (bid < 19000) { y = 3; b0 = bid - 17000; }
  else if (bid < 21000) { y = 4; b0 = bid - 19000; }
  else if (bid < 28500) { y = 5; b0 = bid - 21000; }
  else if (bid < 30500) { y = 6; b0 = bid - 28500; }
  else                  { y = 7; b0 = bid - 30500; }
  int side = y >> 2, r = y & 3;
  int wv = t >> 6, lane = t & 63;
  int n = b0*4 + wv;
  const float* xv = ws + (side ? ((r & 1) ? XT_OFF : XA_OFF) : ((r & 1) ? XA_OFF : XT_OFF));
  float4 wv4 = *(const float4*)(ws + WVB + (size_t)(layer*8 + y)*256 + lane*4);
  float xk = xv[(size_t)n*64 + lane];
  float p0 = wred64(xk * wv4.x);
  float p1 = wred64(xk * wv4.y);
  float p2 = wred64(xk * wv4.z);
  float p3 = wred64(xk * wv4.w);
  if (lane == 0) {
    float4 o; o.x = p0; o.y = p1; o.z = p2; o.w = p3;
    *(float4*)(ws + (side ? selALS(r) : selALD(r)) + (size_t)n*4) = o;
  }
}

// ---------------- h = x_src @ W2 (bf16 interleaved store), flattened grid ----------------
__global__ __launch_bounds__(256) void k_hgemm(float* ws, int layer) {
  int tile = blockIdx.x;          // 4750 tiles: r0:500, r1:1875, r2:500, r3:1875
  int r, row0;
  if (tile < 500)        { r = 0; row0 = tile*16; }
  else if (tile < 2375)  { r = 1; row0 = (tile-500)*16; }
  else if (tile < 2875)  { r = 2; row0 = (tile-2375)*16; }
  else                   { r = 3; row0 = (tile-2875)*16; }
  const float* W2 = ws + W2B + (size_t)(layer*4 + r)*64*256;
  const float* xg = ws + ((r & 1) ? XT_OFF : XA_OFF);
  ushortT* h16 = (ushortT*)(ws + selH(r));
  __shared__ float xs[16][64];
  int t = threadIdx.x;
  #pragma unroll
  for (int i = 0; i < 4; ++i) {
    int lin = i*256 + t;
    xs[lin>>6][lin&63] = xg[((size_t)row0 + (lin>>6))*64 + (lin&63)];
  }
  __syncthreads();
  int c0 = t & 63;
  int tr = t >> 6;
  float acc[4][4];
  #pragma unroll
  for (int i=0;i<4;i++){ acc[i][0]=0;acc[i][1]=0;acc[i][2]=0;acc[i][3]=0; }
  const float* Wc = W2 + c0*4;
  for (int k4 = 0; k4 < 16; ++k4) {
    float4 xv[4];
    #pragma unroll
    for (int i = 0; i < 4; ++i) xv[i] = *(const float4*)&xs[tr*4+i][k4*4];
    #pragma unroll
    for (int kk = 0; kk < 4; ++kk) {
      int k = k4*4 + kk;
      float4 w4 = *(const float4*)(Wc + k*256);
      #pragma unroll
      for (int i = 0; i < 4; ++i) {
        float x = (kk==0)?xv[i].x:(kk==1)?xv[i].y:(kk==2)?xv[i].z:xv[i].w;
        acc[i][0] += x*w4.x; acc[i][1] += x*w4.y; acc[i][2] += x*w4.z; acc[i][3] += x*w4.w;
      }
    }
  }
  #pragma unroll
  for (int i = 0; i < 4; ++i) {
    int row = row0 + tr*4 + i;
    ushort4 pk;
    pk.x = f2bf(acc[i][0]); pk.y = f2bf(acc[i][1]);
    pk.z = f2bf(acc[i][2]); pk.w = f2bf(acc[i][3]);
    *(ushort4*)(h16 + (size_t)row*256 + c0*4) = pk;
  }
}

// ---------------- fused CSR aggregation, flattened grid, agents-first ----------------
__global__ __launch_bounds__(256) void k_agg(const float* convBias, float* ws, int layer) {
  int t = threadIdx.x, wv = t >> 6, lane = t & 63, hh = lane & 3, base = lane & ~3;
  const int* wsi = (const int*)ws;
  int bid = blockIdx.x;
  __shared__ float part[4][64];
  __shared__ float sh1[4][64];
  __shared__ float sh2[4][64];
  if (bid < 4000) {
    int node = bid*2 + (wv >> 1);
    int rr = wv & 1;
    int r = rr ? 3 : 1;
    const int* rp = wsi + ROWP_I + r*RELSTRIDE;
    const int* es = wsi + ESRC_I + r*NE;
    const float* als = ws + selALS(r);
    const ushortT* h16 = (const ushortT*)(ws + selH(r));
    float ad = (ws + selALD(r))[node*4 + hh];
    part[wv][lane] = agg_rel(es, rp[node], rp[node+1], als, h16, ad, lane, hh, base);
    __syncthreads();
    if (rr == 0) {
      float o = part[wv][lane] + part[wv+1][lane];
      float bavg = 0.5f*(convBias[(layer*4 + 1)*64 + lane] + convBias[(layer*4 + 3)*64 + lane]);
      float z = fmaxf(o*0.125f + bavg, 0.f);
      ws[OAACC + (size_t)node*64 + lane] = z;
      sh1[wv][lane] = z; sh2[wv][lane] = z*z;
    } else {
      sh1[wv][lane] = 0.f; sh2[wv][lane] = 0.f;
    }
    __syncthreads();
    if (t < 64) {
      float s1 = sh1[0][t] + sh1[1][t] + sh1[2][t] + sh1[3][t];
      float s2 = sh2[0][t] + sh2[1][t] + sh2[2][t] + sh2[3][t];
      int bucket = bid & 63;
      atomicAdd(&ws[BNSTB + bucket*256 + t], s1);            // bt=0 agent
      atomicAdd(&ws[BNSTB + bucket*256 + 64 + t], s2);
    }
  } else {
    int node = (bid - 4000)*4 + wv;
    float outv = 0.f;
    #pragma unroll
    for (int rr = 0; rr < 2; ++rr) {
      int r = rr ? 2 : 0;
      const int* rp = wsi + ROWP_I + r*RELSTRIDE;
      const int* es = wsi + ESRC_I + r*NE;
      const float* als = ws + selALS(r);
      const ushortT* h16 = (const ushortT*)(ws + selH(r));
      float ad = (ws + selALD(r))[node*4 + hh];
      outv += agg_rel(es, rp[node], rp[node+1], als, h16, ad, lane, hh, base);
    }
    float bavg = 0.5f*(convBias[(layer*4 + 0)*64 + lane] + convBias[(layer*4 + 2)*64 + lane]);
    float z = fmaxf(outv*0.125f + bavg, 0.f);
    ws[OTACC + (size_t)node*64 + lane] = z;
    sh1[wv][lane] = z; sh2[wv][lane] = z*z;
    __syncthreads();
    if (t < 64) {
      float s1 = sh1[0][t] + sh1[1][t] + sh1[2][t] + sh1[3][t];
      float s2 = sh2[0][t] + sh2[1][t] + sh2[2][t] + sh2[3][t];
      int bucket = bid & 63;
      atomicAdd(&ws[BNSTB + bucket*256 + 128 + t], s1);      // bt=1 track
      atomicAdd(&ws[BNSTB + bucket*256 + 192 + t], s2);
    }
  }
}

// ---------------- reduce 64 BN-stat buckets -> BNST; optionally zero critic buckets ----------------
__global__ __launch_bounds__(256) void k_bnred2(float* ws, int zero_cstb) {
  int t = threadIdx.x;
  float s = 0.f;
  #pragma unroll
  for (int b = 0; b < 64; ++b) s += ws[BNSTB + b*256 + t];
  ws[BNST + t] = s;
  if (zero_cstb) {
    for (int i = t; i < 24576; i += 256) ws[CSTB + i] = 0.f;
  }
}

// ---------------- batchnorm + residual, flattened grid (layers 0,1) ----------------
__global__ __launch_bounds__(256) void k_bnnorm(const float* bnG, const float* bnB, float* ws, int layer) {
  int bid = blockIdx.x;
  int type, i;
  if (bid < 2000) { type = 0; i = bid*256 + threadIdx.x; }
  else            { type = 1; i = (bid - 2000)*256 + threadIdx.x; }
  float* acc = ws + (type ? OTACC : OAACC);
  float* x = ws + (type ? XT_OFF : XA_OFF);
  int c = i & 63;
  float Nf = type ? 30000.f : 8000.f;
  float s1 = ws[BNST + type*128 + c], s2 = ws[BNST + type*128 + 64 + c];
  float mu = s1/Nf, var = s2/Nf - mu*mu;
  float g = bnG[(layer*2 + type)*64 + c], b = bnB[(layer*2 + type)*64 + c];
  float y = g*(acc[i]-mu)*rsqrtf(var + 1e-5f) + b;
  if (layer > 0) y += x[i];
  x[i] = y;
}

// ---------------- tail: BN(layer2)+residual -> x, fused bucketed critic stats ----------------
__global__ __launch_bounds__(256) void k_bncrit(const float* bnG, const float* bnB, float* ws) {
  int bid = blockIdx.x;
  int t = threadIdx.x;
  int type, i0;
  if (bid < 2000) { type = 0; i0 = bid*256; }
  else            { type = 1; i0 = (bid-2000)*256; }
  float* acc = ws + (type ? OTACC : OAACC);
  float* x = ws + (type ? XT_OFF : XA_OFF);
  int i = i0 + t;
  int c = i & 63;
  float Nf = type ? 30000.f : 8000.f;
  float s1 = ws[BNST + type*128 + c], s2 = ws[BNST + type*128 + 64 + c];
  float mu = s1/Nf, var = s2/Nf - mu*mu;
  float g = bnG[(2*2+type)*64 + c], b = bnB[(2*2+type)*64 + c];
  float y = g*(acc[i]-mu)*rsqrtf(var+1e-5f) + b + x[i];
  x[i] = y;
  __shared__ float sd[3][256];
  sd[0][t] = y; sd[1][t] = y*y; sd[2][t] = y;
  __syncthreads();
  if (t < 64) {
    float a1 = sd[0][t]+sd[0][t+64]+sd[0][t+128]+sd[0][t+192];
    float a2 = sd[1][t]+sd[1][t+64]+sd[1][t+128]+sd[1][t+192];
    float mx = fmaxf(fmaxf(sd[2][t],sd[2][t+64]), fmaxf(sd[2][t+128],sd[2][t+192]));
    int bucket = bid & 63;
    atomicAdd(&ws[CSTB + bucket*384 + type*192 + t], a1);
    atomicAdd(&ws[CSTB + bucket*384 + type*192 + 64 + t], a2);
    atomicMax((unsigned*)&ws[CSTB + bucket*384 + type*192 + 128 + t], fmap(mx));
  }
}

// ---------------- actor heads: wave per node, both heads in parallel, flattened ----------------
__global__ __launch_bounds__(256) void k_actor(const float* aW1, const float* ab1, const float* ag,
    const float* abe, const float* aW2, const float* ab2, const float* ws, float* out) {
  int bid = blockIdx.x;
  int type, nb;
  if (bid < 2000) { type = 0; nb = bid; } else { type = 1; nb = bid - 2000; }
  int t = threadIdx.x, wv = t >> 6, lane = t & 63;
  int p = lane >> 5, j = lane & 31;
  int n = nb*4 + wv;
  const float* xg = ws + (type ? XT_OFF : XA_OFF);
  __shared__ float xsh[4][64];
  xsh[wv][lane] = xg[(size_t)n*64 + lane];
  __syncthreads();
  int i = (type ? 2 : 0) + p;
  const float* W = aW1 + i*2048 + j;
  float a0 = 0.f, a1 = 0.f, a2 = 0.f, a3 = 0.f;
  #pragma unroll
  for (int k = 0; k < 64; k += 4) {
    a0 += xsh[wv][k]   * W[k*32];
    a1 += xsh[wv][k+1] * W[(k+1)*32];
    a2 += xsh[wv][k+2] * W[(k+2)*32];
    a3 += xsh[wv][k+3] * W[(k+3)*32];
  }
  float tv = ((a0+a1)+(a2+a3)) + ab1[i*32 + j];
  float mu = wred32(tv) * (1.f/32.f);
  float dz = tv - mu;
  float var = wred32(dz*dz) * (1.f/32.f);
  float hn = fmaxf(ag[i*32+j]*dz*rsqrtf(var + 1e-5f) + abe[i*32+j], 0.f);
  float s = wred32(hn * aW2[i*32 + j]) + ab2[i];
  float val = softplusf(s) + 1.f;
  float vA = __shfl(val, 0);
  float vB = __shfl(val, 32);
  if (lane == 0) {
    int offA = type ? 24000 : 0, offB = type ? 54000 : 8000, offC = type ? 84000 : 16000;
    out[offA + n] = vA;
    out[offB + n] = vB;
    out[offC + n] = vA / (vA + vB);
  }
}

__device__ __forceinline__ float blocksum128(float v, float* red) {
  int t = threadIdx.x;
  red[t] = v; __syncthreads();
  #pragma unroll
  for (int s = 64; s > 0; s >>= 1) { if (t < s) red[t] += red[t+s]; __syncthreads(); }
  float r = red[0]; __syncthreads();
  return r;
}

// ---------------- critic MLP (reduces CSTB buckets in prologue) ----------------
__global__ __launch_bounds__(128) void k_critic(const float* cW1,const float* cb1,const float* cg1,const float* cbe1,
    const float* cW2,const float* cb2,const float* cg2,const float* cbe2,
    const float* cW3,const float* cb3,const float* cW4,const float* cb4,
    const float* ws, float* out) {
  __shared__ float g[384];
  __shared__ float h1[128];
  __shared__ float h2s[64];
  __shared__ float red[128];
  int t = threadIdx.x;
  if (t < 64) {
    #pragma unroll
    for (int type = 0; type < 2; ++type) {
      float s1 = 0.f, s2 = 0.f;
      unsigned mu_ = 0u;
      for (int b2 = 0; b2 < 64; ++b2) {
        s1 += ws[CSTB + b2*384 + type*192 + t];
        s2 += ws[CSTB + b2*384 + type*192 + 64 + t];
        unsigned u = __float_as_uint(ws[CSTB + b2*384 + type*192 + 128 + t]);
        mu_ = max(mu_, u);
      }
      float Nf = type ? 30000.f : 8000.f;
      float mean = s1 / Nf;
      float sd = sqrtf(fmaxf((s2 - Nf*mean*mean) / (Nf - 1.f), 0.f));
      g[type*192 + t] = mean;
      g[type*192 + 64 + t] = funmap(mu_);
      g[type*192 + 128 + t] = sd;
    }
  }
  __syncthreads();
  float v = cb1[t];
  for (int k = 0; k < 384; ++k) v += g[k] * cW1[k*128 + t];
  float mu = blocksum128(v, red) * (1.f/128.f);
  float d = v - mu;
  float var = blocksum128(d*d, red) * (1.f/128.f);
  h1[t] = fmaxf(cg1[t]*d*rsqrtf(var + 1e-5f) + cbe1[t], 0.f);
  __syncthreads();
  float v2 = 0.f;
  if (t < 64) { v2 = cb2[t]; for (int k = 0; k < 128; ++k) v2 += h1[k] * cW2[k*64 + t]; }
  float mu2 = blocksum128(t < 64 ? v2 : 0.f, red) * (1.f/64.f);
  float d2 = v2 - mu2;
  float var2 = blocksum128(t < 64 ? d2*d2 : 0.f, red) * (1.f/64.f);
  if (t < 64) h2s[t] = fmaxf(cg2[t]*d2*rsqrtf(var2 + 1e-5f) + cbe2[t], 0.f);
  __syncthreads();
  float v3 = 0.f;
  if (t < 32) {
    v3 = cb3[t];
    for (int k = 0; k < 64; ++k) v3 += h2s[k] * cW3[k*32 + t];
    v3 = fmaxf(v3, 0.f);
  }
  float s4 = blocksum128(t < 32 ? v3 * cW4[t] : 0.f, red);
  if (t == 0) out[114000] = s4 + cb4[0];
}

extern "C" void kernel_launch(void* const* d_in, const int* in_sizes, int n_in,
                              void* d_out, int out_size, void* d_ws, size_t ws_size,
                              hipStream_t stream) {
  const float* x_agent = (const float*)d_in[0];
  const float* x_track = (const float*)d_in[1];
  const int* s0 = (const int*)d_in[2]; const int* d0_ = (const int*)d_in[3];
  const int* s1 = (const int*)d_in[4]; const int* d1_ = (const int*)d_in[5];
  const int* s2 = (const int*)d_in[6]; const int* d2_ = (const int*)d_in[7];
  const int* s3 = (const int*)d_in[8]; const int* d3_ = (const int*)d_in[9];
  const float* aeW = (const float*)d_in[10]; const float* aeB = (const float*)d_in[11];
  const float* teW = (const float*)d_in[12]; const float* teB = (const float*)d_in[13];
  const float* convW    = (const float*)d_in[14];
  const float* convAsrc = (const float*)d_in[15];
  const float* convAdst = (const float*)d_in[16];
  const float* convBias = (const float*)d_in[17];
  const float* bnG = (const float*)d_in[18]; const float* bnB = (const float*)d_in[19];
  const float* aW1 = (const float*)d_in[20]; const float* ab1 = (const float*)d_in[21];
  const float* ag  = (const float*)d_in[22]; const float* abe = (const float*)d_in[23];
  const float* aW2 = (const float*)d_in[24]; const float* ab2 = (const float*)d_in[25];
  const float* cW1 = (const float*)d_in[26]; const float* cb1 = (const float*)d_in[27];
  const float* cg1 = (const float*)d_in[28]; const float* cbe1 = (const float*)d_in[29];
  const float* cW2 = (const float*)d_in[30]; const float* cb2 = (const float*)d_in[31];
  const float* cg2 = (const float*)d_in[32]; const float* cbe2 = (const float*)d_in[33];
  const float* cW3 = (const float*)d_in[34]; const float* cb3 = (const float*)d_in[35];
  const float* cW4 = (const float*)d_in[36]; const float* cb4 = (const float*)d_in[37];
  float* ws = (float*)d_ws;
  int* wsi = (int*)d_ws;
  float* out = (float*)d_out;

  hipMemsetAsync(wsi + ROWP_I, 0, (size_t)240128 * sizeof(int), stream);

  k_pre<<<dim3(11940), 256, 0, stream>>>(x_agent, x_track, aeW, aeB, teW, teB,
                                         d0_, d1_, d2_, d3_, convW, convAsrc, convAdst, ws);
  k_scan<<<dim3(4), 256, 0, stream>>>(wsi);
  k_fill<<<dim3(586, 4), 256, 0, stream>>>(s0,d0_,s1,d1_,s2,d2_,s3,d3_, wsi);

  for (int l = 0; l < 3; ++l) {
    k_alx<<<dim3(38000), 256, 0, stream>>>(ws, l);
    k_hgemm<<<dim3(4750), 256, 0, stream>>>(ws, l);
    k_agg<<<dim3(11500), 256, 0, stream>>>(convBias, ws, l);
    k_bnred2<<<dim3(1), 256, 0, stream>>>(ws, l == 2 ? 1 : 0);
    if (l < 2) k_bnnorm<<<dim3(9500), 256, 0, stream>>>(bnG, bnB, ws, l);
  }

  k_bncrit<<<dim3(9500), 256, 0, stream>>>(bnG, bnB, ws);
  k_actor<<<dim3(9500), 256, 0, stream>>>(aW1, ab1, ag, abe, aW2, ab2, ws, out);
  k_critic<<<1, 128, 0, stream>>>(cW1,cb1,cg1,cbe1,cW2,cb2,cg2,cbe2,cW3,cb3,cW4,cb4, ws, out);
}